// Round 10
// baseline (460.952 us; speedup 1.0000x reference)
//
#include <hip/hip_runtime.h>
#include <math.h>

#define NXc 432
#define NYc 496
#define NVc 10000
#define NPc 16384
#define CELLS (NXc*NYc)          // 214272
#define SHRINKc 0.0025f
#define NVPAD 10048              // 157*64
#define NBX 27
#define NBY 31
#define NBIN (NBX*NBY)           // 837

typedef unsigned short u16;
typedef __attribute__((ext_vector_type(8))) short s16x8;   // 8 bf16
typedef __attribute__((ext_vector_type(4))) float f32x4;

__device__ __forceinline__ unsigned med3u(unsigned a, unsigned b, unsigned c) {
    unsigned d;
    asm("v_med3_u32 %0, %1, %2, %3" : "=v"(d) : "v"(a), "v"(b), "v"(c));
    return d;
}

// ---------------- fp32 -> bf16 (RNE) ----------------
__device__ __forceinline__ u16 f2b(float x) {
    unsigned u = __float_as_uint(x);
    unsigned r = (u + 0x7fffu + ((u >> 16) & 1u)) >> 16;
    return (u16)r;
}

// ---------------- init: stats zero + cellMap=-1 + all bf16 casts ----------------
__global__ __launch_bounds__(256) void k_init(const float* __restrict__ pillar,
                                              const float* __restrict__ pfeat,
                                              const float* __restrict__ memw,
                                              const float* __restrict__ adapt,
                                              float* __restrict__ stats,
                                              int* __restrict__ cellMap,
                                              u16* __restrict__ pillarH,
                                              u16* __restrict__ pfeatH,
                                              u16* __restrict__ memwH,
                                              u16* __restrict__ memwTH,
                                              u16* __restrict__ badaptH) {
    int gid = blockIdx.x * 256 + threadIdx.x;      // 7168*256 = 1835008 exactly
    if (gid < CELLS) cellMap[gid] = -1;
    if (gid < 260) stats[gid] = 0.f;
    const int N1 = NVPAD * 64;                     // 643072
    const int N2 = N1 + NPc * 64;                  // 1691648
    const int N3 = N2 + 65536;                     // 1757184
    const int N4 = N3 + 65536;                     // 1822720  (+12288 = 1835008)
    if (gid < N1) {
        int v = gid >> 6;
        pillarH[gid] = f2b(v < NVc ? pillar[gid] : 0.f);
    } else if (gid < N2) {
        pfeatH[gid - N1] = f2b(pfeat[gid - N1]);
    } else if (gid < N3) {
        memwH[gid - N2] = f2b(memw[gid - N2]);
    } else if (gid < N4) {
        int i = gid - N3;
        int d = i >> 10, j = i & 1023;
        memwTH[i] = f2b(memw[j * 64 + d]);         // memwT[d][j]
    } else {
        int i = gid - N4;                          // 0..12287: Badapt[c][d]
        int c = i >> 6, d = i & 63;
        badaptH[i] = f2b(adapt[(c & 63) * 192 + (c >> 6) * 64 + d]);
    }
}

// ---------------- single-block: histogram + scan + bin fill ----------------
__global__ __launch_bounds__(1024) void k_pre(const float* __restrict__ pcoord,
                                              int* __restrict__ binStart,
                                              float4* __restrict__ binPC) {
    __shared__ int hcnt[1024];
    __shared__ int sc[1024];
    __shared__ int cur[1024];
    int t = threadIdx.x;
    hcnt[t] = 0;
    __syncthreads();
    for (int j = t; j < NPc; j += 1024) {
        float qx = pcoord[j * 4 + 1], qy = pcoord[j * 4 + 2];
        int bx = (int)(qx * 0.0625f); if (bx > NBX - 1) bx = NBX - 1;
        int by = (int)(qy * 0.0625f); if (by > NBY - 1) by = NBY - 1;
        atomicAdd(&hcnt[by * NBX + bx], 1);
    }
    __syncthreads();
    int vcount = (t < NBIN) ? hcnt[t] : 0;
    sc[t] = vcount;
    __syncthreads();
    for (int off = 1; off < 1024; off <<= 1) {
        int add = (t >= off) ? sc[t - off] : 0;
        __syncthreads();
        sc[t] += add;
        __syncthreads();
    }
    int excl = sc[t] - vcount;
    cur[t] = excl;
    if (t <= NBIN) binStart[t] = excl;
    __syncthreads();
    for (int j = t; j < NPc; j += 1024) {
        float qx = pcoord[j * 4 + 1], qy = pcoord[j * 4 + 2], qz = pcoord[j * 4 + 3];
        int bx = (int)(qx * 0.0625f); if (bx > NBX - 1) bx = NBX - 1;
        int by = (int)(qy * 0.0625f); if (by > NBY - 1) by = NBY - 1;
        int slot = atomicAdd(&cur[by * NBX + bx], 1);
        binPC[slot] = make_float4(qx, qy, qz * qz, __uint_as_float((unsigned)j));
    }
}

// ---------------- FUSED: mem (bid<256) | dist6 (256..295) | score (296..2807) ----------------
// All MFMA B-fragments read DIRECTLY from global (L2-resident, reused across blocks).
// LDS = 8 KB (mem-role wave-private transpose tile only). Score/dist: zero LDS, zero barriers.
__global__ __launch_bounds__(256) void k_fused(const u16* __restrict__ pillarH,
                                               const u16* __restrict__ pfeatH,
                                               const u16* __restrict__ memwH,
                                               const u16* __restrict__ memwTH,
                                               const int* __restrict__ coords,
                                               const float4* __restrict__ binPC,
                                               const int* __restrict__ binStart,
                                               u16* __restrict__ PoutH,
                                               int* __restrict__ dIdx6,
                                               int* __restrict__ sIdx) {
    __shared__ u16 STbuf[4][1024];                 // 8 KB, mem role only
    int bid = blockIdx.x;
    int t = threadIdx.x;
    int w = t >> 6, l = t & 63;
    int lm = l & 15, qd = l >> 4;

    if (bid < 256) {
        // ================= mem role: streaming memory_lookup, global-direct B =================
        int pb = bid * 64;
        u16* ST = &STbuf[w][0];
        const u16* arow = pfeatH + (size_t)(pb + 16 * w + lm) * 64 + qd * 8;
        s16x8 a0 = *(const s16x8*)arow;
        s16x8 a1 = *(const s16x8*)(arow + 32);
        float mM[4] = {-INFINITY, -INFINITY, -INFINITY, -INFINITY};
        float Zs[4] = {0.f, 0.f, 0.f, 0.f};
        // pass 1: online (max, sumexp), 4-strip batches
        for (int tile = 0; tile < 16; ++tile) {
            f32x4 acc[4];
#pragma unroll
            for (int st = 0; st < 4; ++st) {
                const u16* brow = memwH + (size_t)(tile * 64 + st * 16 + lm) * 64 + qd * 8;
                s16x8 b0 = *(const s16x8*)brow;
                s16x8 b1 = *(const s16x8*)(brow + 32);
                f32x4 z = {0.f, 0.f, 0.f, 0.f};
                z = __builtin_amdgcn_mfma_f32_16x16x32_bf16(a0, b0, z, 0, 0, 0);
                z = __builtin_amdgcn_mfma_f32_16x16x32_bf16(a1, b1, z, 0, 0, 0);
                acc[st] = z;
            }
#pragma unroll
            for (int r = 0; r < 4; ++r) {
                float tmax = acc[0][r];
#pragma unroll
                for (int st = 1; st < 4; ++st) tmax = fmaxf(tmax, acc[st][r]);
                float mn = fmaxf(mM[r], tmax);
                float zacc = Zs[r] * __expf(mM[r] - mn);
#pragma unroll
                for (int st = 0; st < 4; ++st) zacc += __expf(acc[st][r] - mn);
                mM[r] = mn; Zs[r] = zacc;
            }
        }
#pragma unroll
        for (int r = 0; r < 4; ++r) {
#pragma unroll
            for (int off = 1; off < 16; off <<= 1) {
                float om = __shfl_xor(mM[r], off);
                float oz = __shfl_xor(Zs[r], off);
                float mn = fmaxf(mM[r], om);
                Zs[r] = Zs[r] * __expf(mM[r] - mn) + oz * __expf(om - mn);
                mM[r] = mn;
            }
        }
        float invZ[4], L1[4] = {0.f, 0.f, 0.f, 0.f};
#pragma unroll
        for (int r = 0; r < 4; ++r) invZ[r] = 1.f / Zs[r];
        f32x4 oacc[4];
#pragma unroll
        for (int n = 0; n < 4; ++n) oacc[n] = (f32x4){0.f, 0.f, 0.f, 0.f};
        // pass 2: recompute, shrink, wave-private LDS transpose, out-MFMA (global-direct WT)
        for (int tile = 0; tile < 16; ++tile) {
#pragma unroll
            for (int st = 0; st < 4; ++st) {
                const u16* brow = memwH + (size_t)(tile * 64 + st * 16 + lm) * 64 + qd * 8;
                s16x8 b0 = *(const s16x8*)brow;
                s16x8 b1 = *(const s16x8*)(brow + 32);
                f32x4 z = {0.f, 0.f, 0.f, 0.f};
                z = __builtin_amdgcn_mfma_f32_16x16x32_bf16(a0, b0, z, 0, 0, 0);
                z = __builtin_amdgcn_mfma_f32_16x16x32_bf16(a1, b1, z, 0, 0, 0);
                int g2 = st * 2 + (lm >> 3);       // [0,8)
#pragma unroll
                for (int r = 0; r < 4; ++r) {
                    float e = __expf(z[r] - mM[r]);
                    float a = e * invZ[r];
                    float tt = a - SHRINKc;
                    float sres = fmaxf(tt, 0.f) * a / (fabsf(tt) + 1e-12f);
                    L1[r] += sres;
                    int rr = qd * 4 + r;
                    ST[(g2 * 16 + (rr ^ g2)) * 8 + (lm & 7)] = f2b(sres);
                }
            }
            // wave-private ST: program-order ds dependency, no block barrier
#pragma unroll
            for (int ks = 0; ks < 2; ++ks) {
                int g = ks * 4 + qd;               // [0,8)
                s16x8 af = *(const s16x8*)&ST[(g * 16 + (lm ^ g)) * 8];
#pragma unroll
                for (int n = 0; n < 4; ++n) {
                    s16x8 bf = *(const s16x8*)(memwTH
                        + (size_t)(n * 16 + lm) * 1024 + tile * 64 + g * 8);
                    oacc[n] = __builtin_amdgcn_mfma_f32_16x16x32_bf16(af, bf, oacc[n], 0, 0, 0);
                }
            }
        }
#pragma unroll
        for (int r = 0; r < 4; ++r) {
#pragma unroll
            for (int off = 1; off < 16; off <<= 1) L1[r] += __shfl_xor(L1[r], off);
            L1[r] = 1.f / fmaxf(L1[r], 1e-12f);
        }
#pragma unroll
        for (int n = 0; n < 4; ++n)
#pragma unroll
            for (int r = 0; r < 4; ++r)
                PoutH[(size_t)(pb + 16 * w + qd * 4 + r) * 64 + n * 16 + lm] =
                    f2b(oacc[n][r] * L1[r]);
    } else if (bid < 296) {
        // ================= dist6 role: bin ring search =================
        int v = (bid - 256) * 256 + t;             // 40*256 = 10240
        if (v >= NVc) return;
        int xi = coords[v * 4 + 1], yi = coords[v * 4 + 2];
        float x = (float)xi, y = (float)yi;
        int bx = xi >> 4; if (bx > NBX - 1) bx = NBX - 1;
        int by = yi >> 4; if (by > NBY - 1) by = NBY - 1;
        unsigned kk[6] = {~0u, ~0u, ~0u, ~0u, ~0u, ~0u};
        for (int r = 0; r < 32; ++r) {
            int x0 = bx - r, x1 = bx + r, y0 = by - r, y1 = by + r;
            for (int cy = y0; cy <= y1; ++cy) {
                if (cy < 0 || cy > NBY - 1) continue;
                int step = (cy == y0 || cy == y1) ? 1 : (x1 > x0 ? x1 - x0 : 1);
                for (int cx = x0; cx <= x1; cx += step) {
                    if (cx < 0 || cx > NBX - 1) continue;
                    int b = cy * NBX + cx;
                    int s0 = binStart[b], s1 = binStart[b + 1];
                    for (int s = s0; s < s1; ++s) {
                        float4 p = binPC[s];
                        float e1 = x - p.x, e2 = y - p.y;
                        float d2 = fmaf(e1, e1, fmaf(e2, e2, p.z));
                        unsigned tk = (__float_as_uint(d2) & 0xFFFFC000u) | __float_as_uint(p.w);
                        kk[5] = med3u(kk[4], kk[5], tk);
                        kk[4] = med3u(kk[3], kk[4], tk);
                        kk[3] = med3u(kk[2], kk[3], tk);
                        kk[2] = med3u(kk[1], kk[2], tk);
                        kk[1] = med3u(kk[0], kk[1], tk);
                        kk[0] = kk[0] < tk ? kk[0] : tk;
                    }
                }
            }
            if (kk[2] != ~0u) {
                float d3 = __uint_as_float(kk[2] & 0xFFFFC000u);
                if (256.f * (float)(r * r) > d3 * 1.004f + 1e-3f) break;
            }
        }
#pragma unroll
        for (int j2 = 0; j2 < 6; ++j2) dIdx6[v * 6 + j2] = (int)(kk[j2] & 16383u);
    } else {
        // ================= score role: global-direct B, zero LDS, zero barriers =================
        int sb = bid - 296;                        // 0..2511
        int pb = (sb >> 4) * 64;                   // 157 pillar tiles
        int cb = (sb & 15) * 1024;                 // 16 chunks
        const u16* arow = pillarH + (size_t)(pb + 16 * w + lm) * 64 + qd * 8;
        s16x8 a0 = *(const s16x8*)arow;
        s16x8 a1 = *(const s16x8*)(arow + 32);
        unsigned sk[4][4];
#pragma unroll
        for (int r = 0; r < 4; ++r)
#pragma unroll
            for (int j = 0; j < 4; ++j) sk[r][j] = 0u;
        for (int s = 0; s < 8; ++s) {
            const u16* base = pfeatH + (size_t)(cb + s * 128) * 64;
#pragma unroll
            for (int pt = 0; pt < 8; ++pt) {
                const u16* brow = base + (size_t)(pt * 16 + lm) * 64 + qd * 8;
                s16x8 b0 = *(const s16x8*)brow;
                s16x8 b1 = *(const s16x8*)(brow + 32);
                f32x4 acc = {256.f, 256.f, 256.f, 256.f};
                acc = __builtin_amdgcn_mfma_f32_16x16x32_bf16(a0, b0, acc, 0, 0, 0);
                acc = __builtin_amdgcn_mfma_f32_16x16x32_bf16(a1, b1, acc, 0, 0, 0);
                unsigned idf = (unsigned)(1023 - (s * 128 + pt * 16 + lm));
#pragma unroll
                for (int r = 0; r < 4; ++r) {
                    unsigned key = (__float_as_uint(acc[r]) & 0xFFFFFC00u) | idf;
                    sk[r][3] = med3u(sk[r][2], sk[r][3], key);
                    sk[r][2] = med3u(sk[r][1], sk[r][2], key);
                    sk[r][1] = med3u(sk[r][0], sk[r][1], key);
                    sk[r][0] = sk[r][0] > key ? sk[r][0] : key;
                }
            }
        }
        // butterfly merge across the 16 lanes of each quad (contiguous lanes, xor<16)
#pragma unroll
        for (int off = 1; off < 16; off <<= 1) {
#pragma unroll
            for (int r = 0; r < 4; ++r) {
                unsigned o0 = __shfl_xor(sk[r][0], off);
                unsigned o1 = __shfl_xor(sk[r][1], off);
                unsigned o2 = __shfl_xor(sk[r][2], off);
                unsigned o3 = __shfl_xor(sk[r][3], off);
                sk[r][3] = med3u(sk[r][2], sk[r][3], o0);
                sk[r][2] = med3u(sk[r][1], sk[r][2], o0);
                sk[r][1] = med3u(sk[r][0], sk[r][1], o0);
                sk[r][0] = sk[r][0] > o0 ? sk[r][0] : o0;
                sk[r][3] = med3u(sk[r][2], sk[r][3], o1);
                sk[r][2] = med3u(sk[r][1], sk[r][2], o1);
                sk[r][1] = med3u(sk[r][0], sk[r][1], o1);
                sk[r][0] = sk[r][0] > o1 ? sk[r][0] : o1;
                sk[r][3] = med3u(sk[r][2], sk[r][3], o2);
                sk[r][2] = med3u(sk[r][1], sk[r][2], o2);
                sk[r][1] = med3u(sk[r][0], sk[r][1], o2);
                sk[r][0] = sk[r][0] > o2 ? sk[r][0] : o2;
                sk[r][3] = med3u(sk[r][2], sk[r][3], o3);
                sk[r][2] = med3u(sk[r][1], sk[r][2], o3);
                sk[r][1] = med3u(sk[r][0], sk[r][1], o3);
                sk[r][0] = sk[r][0] > o3 ? sk[r][0] : o3;
            }
        }
        if (lm == 0) {
            int chunk = sb & 15;
#pragma unroll
            for (int r = 0; r < 4; ++r) {
                int gpr = pb + 16 * w + qd * 4 + r;
                if (gpr < NVc) {
                    int4 v;
                    v.x = cb + 1023 - (int)(sk[r][0] & 1023u);
                    v.y = cb + 1023 - (int)(sk[r][1] & 1023u);
                    v.z = cb + 1023 - (int)(sk[r][2] & 1023u);
                    v.w = cb + 1023 - (int)(sk[r][3] & 1023u);
                    *(int4*)&sIdx[(chunk * NVc + gpr) * 4] = v;
                }
            }
        }
    }
}

// ---------------- FUSED-2: proj2 (bid<256, global-direct B) | fp64 rerank ----------------
__global__ __launch_bounds__(256) void k_fused2(const u16* __restrict__ PoutH,
                                                const u16* __restrict__ badaptH,
                                                const float* __restrict__ pillar,
                                                const int* __restrict__ coords,
                                                const float* __restrict__ pfeat,
                                                const float* __restrict__ pcoord,
                                                const int* __restrict__ sIdx,
                                                const int* __restrict__ dIdx6,
                                                float* __restrict__ Q,
                                                int* __restrict__ idx_f,
                                                int* __restrict__ idx_c) {
    int bid = blockIdx.x;
    int t = threadIdx.x;
    if (bid < 256) {
        int w = t >> 6, l = t & 63;
        int lm = l & 15, qd = l >> 4;
        int pb = bid * 64;
        const u16* arow = PoutH + (size_t)(pb + 16 * w + lm) * 64 + qd * 8;
        s16x8 a0 = *(const s16x8*)arow;
        s16x8 a1 = *(const s16x8*)(arow + 32);
        f32x4 acc[12];
#pragma unroll
        for (int nt = 0; nt < 12; ++nt) {
            const u16* brow = badaptH + (size_t)(nt * 16 + lm) * 64 + qd * 8;
            s16x8 b0 = *(const s16x8*)brow;
            s16x8 b1 = *(const s16x8*)(brow + 32);
            f32x4 z = {0.f, 0.f, 0.f, 0.f};
            z = __builtin_amdgcn_mfma_f32_16x16x32_bf16(a0, b0, z, 0, 0, 0);
            z = __builtin_amdgcn_mfma_f32_16x16x32_bf16(a1, b1, z, 0, 0, 0);
            acc[nt] = z;
        }
#pragma unroll
        for (int nt = 0; nt < 12; ++nt)
#pragma unroll
            for (int r = 0; r < 4; ++r)
                Q[(size_t)(pb + 16 * w + qd * 4 + r) * 192 + nt * 16 + lm] = acc[nt][r];
    } else {
        int wv = t >> 6, l = t & 63;
        int v = (bid - 256) * 4 + wv;
        int chunk = l >> 2, slot = l & 3;
        int ps = sIdx[(chunk * NVc + v) * 4 + slot];
        int pd = dIdx6[v * 6 + (l < 6 ? l : 0)];
        double s = 0.0;
#pragma unroll
        for (int i = 0; i < 16; ++i) {
            float4 a = *(const float4*)(pillar + v * 64 + 4 * i);
            float4 b = *(const float4*)(pfeat + ps * 64 + 4 * i);
            s += (double)a.x * (double)b.x + (double)a.y * (double)b.y
               + (double)a.z * (double)b.z + (double)a.w * (double)b.w;
        }
        float4 qc = *(const float4*)(pcoord + pd * 4);
        double db_ = (double)coords[v * 4 + 0] - (double)qc.x;
        double dx_ = (double)coords[v * 4 + 1] - (double)qc.y;
        double dy_ = (double)coords[v * 4 + 2] - (double)qc.z;
        double dz_ = (double)coords[v * 4 + 3] - (double)qc.w;
        double d2 = db_ * db_ + dx_ * dx_ + dy_ * dy_ + dz_ * dz_;
        double sv = s; int sx = ps;
        for (int k = 0; k < 3; ++k) {
            double bv = sv; int bi = sx;
#pragma unroll
            for (int off = 32; off >= 1; off >>= 1) {
                double ov = __shfl_xor(bv, off);
                int    oi = __shfl_xor(bi, off);
                if (ov > bv || (ov == bv && oi < bi)) { bv = ov; bi = oi; }
            }
            if (l == 0) idx_f[v * 3 + k] = bi;
            if (sx == bi) { sv = -INFINITY; sx = 0x7fffffff; }
        }
        double dv = d2; int dx2 = pd;
        for (int k = 0; k < 3; ++k) {
            double bv = dv; int bi = dx2;
#pragma unroll
            for (int off = 32; off >= 1; off >>= 1) {
                double ov = __shfl_xor(bv, off);
                int    oi = __shfl_xor(bi, off);
                if (ov < bv || (ov == bv && oi < bi)) { bv = ov; bi = oi; }
            }
            if (l == 0) idx_c[v * 3 + k] = bi;
            if (dx2 == bi) { dv = INFINITY; dx2 = 0x7fffffff; }
        }
    }
}

// ---------------- gather-add + w logits + BN partial sums + cellMap scatter ----------------
__global__ __launch_bounds__(256) void k_gather(const float* __restrict__ Q,
                                                const int* __restrict__ idx_f,
                                                const int* __restrict__ idx_c,
                                                const float* __restrict__ pillar,
                                                const int* __restrict__ coords,
                                                const float* __restrict__ ww,
                                                float* __restrict__ f_pre,
                                                float* __restrict__ c_pre,
                                                float* __restrict__ w_pre,
                                                float* __restrict__ stats,
                                                int* __restrict__ cellMap) {
    __shared__ float red[4][4][64];
    __shared__ float redw[4][4];
    int t = threadIdx.x;
    int wv = t >> 6, l = t & 63;
    int base = blockIdx.x * 40;
    int vend = base + 40;
    if (t < 40) {
        int v = base + t;
        int cell = coords[v * 4 + 1] + coords[v * 4 + 2] * NXc + coords[v * 4 + 3];
        cellMap[cell] = v;
    }
    float fs = 0, fq = 0, cs = 0, cq = 0, ws0 = 0, wq0 = 0, ws1 = 0, wq1 = 0;
    float w0l = ww[l], w1l = ww[64 + l];
    for (int v = base + wv; v < vend; v += 4) {
        int if0 = idx_f[v * 3], if1 = idx_f[v * 3 + 1], if2 = idx_f[v * 3 + 2];
        float f = Q[if0 * 192 + l] + Q[if1 * 192 + 64 + l] + Q[if2 * 192 + 128 + l];
        f_pre[v * 64 + l] = f; fs += f; fq += f * f;
        int ic0 = idx_c[v * 3], ic1 = idx_c[v * 3 + 1], ic2 = idx_c[v * 3 + 2];
        float c = Q[ic0 * 192 + l] + Q[ic1 * 192 + 64 + l] + Q[ic2 * 192 + 128 + l];
        c_pre[v * 64 + l] = c; cs += c; cq += c * c;
        float pv = pillar[v * 64 + l];
        float a0 = pv * w0l, a1 = pv * w1l;
#pragma unroll
        for (int off = 32; off >= 1; off >>= 1) {
            a0 += __shfl_xor(a0, off);
            a1 += __shfl_xor(a1, off);
        }
        if (l == 0) { w_pre[v * 2] = a0; w_pre[v * 2 + 1] = a1; }
        ws0 += a0; wq0 += a0 * a0; ws1 += a1; wq1 += a1 * a1;
    }
    red[0][wv][l] = fs; red[1][wv][l] = fq; red[2][wv][l] = cs; red[3][wv][l] = cq;
    if (l == 0) { redw[wv][0] = ws0; redw[wv][1] = wq0; redw[wv][2] = ws1; redw[wv][3] = wq1; }
    __syncthreads();
    if (wv == 0) {
#pragma unroll
        for (int q = 0; q < 4; ++q) {
            float sum = red[q][0][l] + red[q][1][l] + red[q][2][l] + red[q][3][l];
            atomicAdd(&stats[q * 64 + l], sum);
        }
        if (l < 4) {
            float sum = redw[0][l] + redw[1][l] + redw[2][l] + redw[3][l];
            atomicAdd(&stats[256 + l], sum);
        }
    }
}

// ---------------- full-canvas write with inline BN/softmax aug ----------------
__global__ __launch_bounds__(256) void k_out2(const int* __restrict__ cellMap,
                                              const float* __restrict__ pillar,
                                              const float* __restrict__ f_pre,
                                              const float* __restrict__ c_pre,
                                              const float* __restrict__ w_pre,
                                              const float* __restrict__ stats,
                                              const float* __restrict__ g1,
                                              const float* __restrict__ b1,
                                              const float* __restrict__ g2,
                                              const float* __restrict__ b2,
                                              float* __restrict__ out) {
    int c4 = (blockIdx.x * 256 + threadIdx.x) * 4;
    if (c4 >= CELLS) return;
    int4 cm = *(const int4*)(cellMap + c4);
    const float invn = 1.0f / (float)NVc;
    float mw0 = stats[256] * invn, vw0 = stats[257] * invn - mw0 * mw0;
    float mw1 = stats[258] * invn, vw1 = stats[259] * invn - mw1 * mw1;
    float rw0 = rsqrtf(vw0 + 1e-3f), rw1 = rsqrtf(vw1 + 1e-3f);
    float g20 = g2[0], b20 = b2[0], g21 = g2[1], b21 = b2[1];
    float w0c[4], w1c[4];
    int cms[4] = {cm.x, cm.y, cm.z, cm.w};
#pragma unroll
    for (int k = 0; k < 4; ++k) {
        int c = cms[k];
        if (c >= 0) {
            float z0 = (w_pre[c * 2] - mw0) * rw0 * g20 + b20;
            float z1 = (w_pre[c * 2 + 1] - mw1) * rw1 * g21 + b21;
            float mz = fmaxf(z0, z1);
            float e0 = __expf(z0 - mz), e1 = __expf(z1 - mz);
            float wd = 1.f / (e0 + e1);
            w0c[k] = e0 * wd; w1c[k] = e1 * wd;
        } else { w0c[k] = 0.f; w1c[k] = 0.f; }
    }
    int f0 = blockIdx.y * 33;
    int f1 = f0 + 33; if (f1 > 131) f1 = 131;
    for (int f = f0; f < f1; ++f) {
        float4 val;
        if (f < 64) {
            val.x = cm.x >= 0 ? pillar[cm.x * 64 + f] : 0.f;
            val.y = cm.y >= 0 ? pillar[cm.y * 64 + f] : 0.f;
            val.z = cm.z >= 0 ? pillar[cm.z * 64 + f] : 0.f;
            val.w = cm.w >= 0 ? pillar[cm.w * 64 + f] : 0.f;
        } else if (f < 128) {
            int fa = f - 64;
            float mf = stats[fa] * invn;
            float rf = rsqrtf(stats[64 + fa] * invn - mf * mf + 1e-3f);
            float mc = stats[128 + fa] * invn;
            float rc = rsqrtf(stats[192 + fa] * invn - mc * mc + 1e-3f);
            float gg = g1[fa], bb = b1[fa];
            float* vv = (float*)&val;
#pragma unroll
            for (int k = 0; k < 4; ++k) {
                int c = cms[k];
                if (c >= 0) {
                    float fv = fmaxf((f_pre[c * 64 + fa] - mf) * rf * gg + bb, 0.f);
                    float cv = fmaxf((c_pre[c * 64 + fa] - mc) * rc * gg + bb, 0.f);
                    vv[k] = w0c[k] * fv + w1c[k] * cv;
                } else vv[k] = 0.f;
            }
        } else if (f == 128) {
            val.x = cm.x >= 0 ? (float)((c4 + 0) / NXc) : 0.f;
            val.y = cm.y >= 0 ? (float)((c4 + 1) / NXc) : 0.f;
            val.z = cm.z >= 0 ? (float)((c4 + 2) / NXc) : 0.f;
            val.w = cm.w >= 0 ? (float)((c4 + 3) / NXc) : 0.f;
        } else if (f == 129) {
            val = make_float4(0.f, 0.f, 0.f, 0.f);
        } else {
            val.x = cm.x >= 0 ? (float)((c4 + 0) % NXc) : 0.f;
            val.y = cm.y >= 0 ? (float)((c4 + 1) % NXc) : 0.f;
            val.z = cm.z >= 0 ? (float)((c4 + 2) % NXc) : 0.f;
            val.w = cm.w >= 0 ? (float)((c4 + 3) % NXc) : 0.f;
        }
        *(float4*)(out + (size_t)f * CELLS + c4) = val;
    }
}

extern "C" void kernel_launch(void* const* d_in, const int* in_sizes, int n_in,
                              void* d_out, int out_size, void* d_ws, size_t ws_size,
                              hipStream_t stream) {
    const float* pillar = (const float*)d_in[0];
    const int*   coords = (const int*)d_in[1];
    const float* pfeat  = (const float*)d_in[2];
    const float* pcoord = (const float*)d_in[3];
    const float* adapt  = (const float*)d_in[4];
    const float* bn1g   = (const float*)d_in[5];
    const float* bn1b   = (const float*)d_in[6];
    const float* ww     = (const float*)d_in[7];
    const float* bn2g   = (const float*)d_in[8];
    const float* bn2b   = (const float*)d_in[9];
    const float* memw   = (const float*)d_in[10];
    float* out = (float*)d_out;
    float* ws  = (float*)d_ws;
    // workspace layout (float offsets)
    u16*   PoutH = (u16*)(ws + 0);                 // 1,048,576 u16
    float* Q     = ws + 1048576;                   // 3,145,728 fl
    int*   sIdx  = (int*)(ws + 4194304);           // 640,000
    int*   binStart  = (int*)(ws + 4834304);       // 838
    int*   dIdx6     = (int*)(ws + 4836824);       // 60,000
    float4* binPC    = (float4*)(ws + 4896824);    // 65,536 fl
    u16*   memwH   = (u16*)(ws + 4970000);         // 65,536 u16
    u16*   memwTH  = (u16*)(ws + 5002768);         // 65,536 u16
    u16*   badaptH = (u16*)(ws + 5035536);         // 12,288 u16
    int*   idxf  = (int*)(ws + 5474304);           // 30,000
    int*   idxc  = (int*)(ws + 5504304);           // 30,000
    float* fpre  = ws + 5534304;                   // 640,000
    float* cpre  = ws + 6174304;                   // 640,000
    float* wpre  = ws + 6814304;                   // 20,000
    float* stats = ws + 6834304;                   // 260
    int*   cellMap = (int*)(ws + 6840000);         // 214,272 ints
    // bf16 feature buffers overlap fpre/cpre (dead until k_gather writes them)
    u16* pillarH = (u16*)(ws + 5534304);           // 643,072 u16
    u16* pfeatH  = pillarH + (size_t)NVPAD * 64;   // 1,048,576 u16

    k_init  <<<7168, 256, 0, stream>>>(pillar, pfeat, memw, adapt, stats, cellMap,
                                       pillarH, pfeatH, memwH, memwTH, badaptH);
    k_pre   <<<1, 1024, 0, stream>>>(pcoord, binStart, binPC);
    k_fused <<<2808, 256, 0, stream>>>(pillarH, pfeatH, memwH, memwTH, coords,
                                       binPC, binStart, PoutH, dIdx6, sIdx);
    k_fused2<<<2756, 256, 0, stream>>>(PoutH, badaptH, pillar, coords, pfeat, pcoord,
                                       sIdx, dIdx6, Q, idxf, idxc);
    k_gather<<<250, 256, 0, stream>>>(Q, idxf, idxc, pillar, coords, ww,
                                      fpre, cpre, wpre, stats, cellMap);
    k_out2  <<<dim3(210, 4), 256, 0, stream>>>(cellMap, pillar, fpre, cpre, wpre, stats,
                                               bn1g, bn1b, bn2g, bn2b, out);
}

// Round 11
// 323.656 us; speedup vs baseline: 1.4242x; 1.4242x over previous
//
#include <hip/hip_runtime.h>
#include <math.h>

#define NXc 432
#define NYc 496
#define NVc 10000
#define NPc 16384
#define CELLS (NXc*NYc)          // 214272
#define SHRINKc 0.0025f
#define NVPAD 10048              // 157*64
#define NBX 27
#define NBY 31
#define NBIN (NBX*NBY)           // 837

typedef unsigned short u16;
typedef __attribute__((ext_vector_type(8))) short s16x8;   // 8 bf16
typedef __attribute__((ext_vector_type(4))) float f32x4;

__device__ __forceinline__ unsigned med3u(unsigned a, unsigned b, unsigned c) {
    unsigned d;
    asm("v_med3_u32 %0, %1, %2, %3" : "=v"(d) : "v"(a), "v"(b), "v"(c));
    return d;
}

// ---------------- fp32 -> bf16 (RNE) ----------------
__device__ __forceinline__ u16 f2b(float x) {
    unsigned u = __float_as_uint(x);
    unsigned r = (u + 0x7fffu + ((u >> 16) & 1u)) >> 16;
    return (u16)r;
}

// ---------------- init: stats zero + cellMap=-1 + all bf16 casts ----------------
__global__ __launch_bounds__(256) void k_init(const float* __restrict__ pillar,
                                              const float* __restrict__ pfeat,
                                              const float* __restrict__ memw,
                                              const float* __restrict__ adapt,
                                              float* __restrict__ stats,
                                              int* __restrict__ cellMap,
                                              u16* __restrict__ pillarH,
                                              u16* __restrict__ pfeatH,
                                              u16* __restrict__ memwH,
                                              u16* __restrict__ memwTH,
                                              u16* __restrict__ badaptH) {
    int gid = blockIdx.x * 256 + threadIdx.x;      // 7168*256 = 1835008 exactly
    if (gid < CELLS) cellMap[gid] = -1;
    if (gid < 260) stats[gid] = 0.f;
    const int N1 = NVPAD * 64;                     // 643072
    const int N2 = N1 + NPc * 64;                  // 1691648
    const int N3 = N2 + 65536;                     // 1757184
    const int N4 = N3 + 65536;                     // 1822720  (+12288 = 1835008)
    if (gid < N1) {
        int v = gid >> 6;
        pillarH[gid] = f2b(v < NVc ? pillar[gid] : 0.f);
    } else if (gid < N2) {
        pfeatH[gid - N1] = f2b(pfeat[gid - N1]);
    } else if (gid < N3) {
        memwH[gid - N2] = f2b(memw[gid - N2]);
    } else if (gid < N4) {
        int i = gid - N3;
        int d = i >> 10, j = i & 1023;
        memwTH[i] = f2b(memw[j * 64 + d]);         // memwT[d][j]
    } else {
        int i = gid - N4;                          // 0..12287: Badapt[c][d]
        int c = i >> 6, d = i & 63;
        badaptH[i] = f2b(adapt[(c & 63) * 192 + (c >> 6) * 64 + d]);
    }
}

// ---------------- single-block: histogram + scan + bin fill ----------------
__global__ __launch_bounds__(1024) void k_pre(const float* __restrict__ pcoord,
                                              int* __restrict__ binStart,
                                              float4* __restrict__ binPC) {
    __shared__ int hcnt[1024];
    __shared__ int sc[1024];
    __shared__ int cur[1024];
    int t = threadIdx.x;
    hcnt[t] = 0;
    __syncthreads();
    for (int j = t; j < NPc; j += 1024) {
        float qx = pcoord[j * 4 + 1], qy = pcoord[j * 4 + 2];
        int bx = (int)(qx * 0.0625f); if (bx > NBX - 1) bx = NBX - 1;
        int by = (int)(qy * 0.0625f); if (by > NBY - 1) by = NBY - 1;
        atomicAdd(&hcnt[by * NBX + bx], 1);
    }
    __syncthreads();
    int vcount = (t < NBIN) ? hcnt[t] : 0;
    sc[t] = vcount;
    __syncthreads();
    for (int off = 1; off < 1024; off <<= 1) {
        int add = (t >= off) ? sc[t - off] : 0;
        __syncthreads();
        sc[t] += add;
        __syncthreads();
    }
    int excl = sc[t] - vcount;
    cur[t] = excl;
    if (t <= NBIN) binStart[t] = excl;
    __syncthreads();
    for (int j = t; j < NPc; j += 1024) {
        float qx = pcoord[j * 4 + 1], qy = pcoord[j * 4 + 2], qz = pcoord[j * 4 + 3];
        int bx = (int)(qx * 0.0625f); if (bx > NBX - 1) bx = NBX - 1;
        int by = (int)(qy * 0.0625f); if (by > NBY - 1) by = NBY - 1;
        int slot = atomicAdd(&cur[by * NBX + bx], 1);
        binPC[slot] = make_float4(qx, qy, qz * qz, __uint_as_float((unsigned)j));
    }
}

// ---------------- FUSED: mem (bid<256) | dist6 (256..295) | score (296..2807) ----------------
// Score role: double-buffered 32 KB LDS staging (best measured: R8=81us) +
// register butterfly merge (verified in R10). Mem role: 24 KB LDS staging (R9).
__global__ __launch_bounds__(256) void k_fused(const u16* __restrict__ pillarH,
                                               const u16* __restrict__ pfeatH,
                                               const u16* __restrict__ memwH,
                                               const u16* __restrict__ memwTH,
                                               const int* __restrict__ coords,
                                               const float4* __restrict__ binPC,
                                               const int* __restrict__ binStart,
                                               u16* __restrict__ PoutH,
                                               int* __restrict__ dIdx6,
                                               int* __restrict__ sIdx) {
    __shared__ union {
        u16 bf[2][8192];                           // score role: 32 KB dbuf
        struct { u16 wh[4096]; u16 wt[4096]; u16 st[4][1024]; } m;   // mem role: 24 KB
    } smem;
    int bid = blockIdx.x;
    int t = threadIdx.x;
    int w = t >> 6, l = t & 63;
    int lm = l & 15, qd = l >> 4;

    if (bid < 256) {
        // ================= mem role: streaming memory_lookup, 64-row LDS tiles =================
        int pb = bid * 64;
        u16* WH = smem.m.wh;
        u16* WT = smem.m.wt;
        u16* ST = &smem.m.st[w][0];
        const u16* arow = pfeatH + (size_t)(pb + 16 * w + lm) * 64 + qd * 8;
        s16x8 a0 = *(const s16x8*)arow;
        s16x8 a1 = *(const s16x8*)(arow + 32);
        float mM[4] = {-INFINITY, -INFINITY, -INFINITY, -INFINITY};
        float Zs[4] = {0.f, 0.f, 0.f, 0.f};
        for (int tile = 0; tile < 16; ++tile) {
            __syncthreads();
#pragma unroll
            for (int r = 0; r < 2; ++r) {
                int q = t + 256 * r;               // 512 granules
                int row = q >> 3, g = q & 7;
                uint4 v = *(const uint4*)(memwH + (size_t)(tile * 64 + row) * 64 + g * 8);
                *(uint4*)&WH[(((row >> 4) * 8 + g) * 16 + ((row & 15) ^ g)) * 8] = v;
            }
            __syncthreads();
            f32x4 acc[4];
#pragma unroll
            for (int st = 0; st < 4; ++st) {
                s16x8 b0 = *(const s16x8*)&WH[((st * 8 + qd) * 16 + (lm ^ qd)) * 8];
                s16x8 b1 = *(const s16x8*)&WH[((st * 8 + qd + 4) * 16 + (lm ^ (qd + 4))) * 8];
                f32x4 z = {0.f, 0.f, 0.f, 0.f};
                z = __builtin_amdgcn_mfma_f32_16x16x32_bf16(a0, b0, z, 0, 0, 0);
                z = __builtin_amdgcn_mfma_f32_16x16x32_bf16(a1, b1, z, 0, 0, 0);
                acc[st] = z;
            }
#pragma unroll
            for (int r = 0; r < 4; ++r) {
                float tmax = acc[0][r];
#pragma unroll
                for (int st = 1; st < 4; ++st) tmax = fmaxf(tmax, acc[st][r]);
                float mn = fmaxf(mM[r], tmax);
                float zacc = Zs[r] * __expf(mM[r] - mn);
#pragma unroll
                for (int st = 0; st < 4; ++st) zacc += __expf(acc[st][r] - mn);
                mM[r] = mn; Zs[r] = zacc;
            }
        }
#pragma unroll
        for (int r = 0; r < 4; ++r) {
#pragma unroll
            for (int off = 1; off < 16; off <<= 1) {
                float om = __shfl_xor(mM[r], off);
                float oz = __shfl_xor(Zs[r], off);
                float mn = fmaxf(mM[r], om);
                Zs[r] = Zs[r] * __expf(mM[r] - mn) + oz * __expf(om - mn);
                mM[r] = mn;
            }
        }
        float invZ[4], L1[4] = {0.f, 0.f, 0.f, 0.f};
#pragma unroll
        for (int r = 0; r < 4; ++r) invZ[r] = 1.f / Zs[r];
        f32x4 oacc[4];
#pragma unroll
        for (int n = 0; n < 4; ++n) oacc[n] = (f32x4){0.f, 0.f, 0.f, 0.f};
        for (int tile = 0; tile < 16; ++tile) {
            __syncthreads();
#pragma unroll
            for (int r = 0; r < 2; ++r) {
                int q = t + 256 * r;
                int row = q >> 3, g = q & 7;
                uint4 v = *(const uint4*)(memwH + (size_t)(tile * 64 + row) * 64 + g * 8);
                *(uint4*)&WH[(((row >> 4) * 8 + g) * 16 + ((row & 15) ^ g)) * 8] = v;
            }
#pragma unroll
            for (int r = 0; r < 2; ++r) {
                int q = t + 256 * r;
                int row = q >> 3, g = q & 7;   // row = n in [0,64)
                uint4 v = *(const uint4*)(memwTH + (size_t)row * 1024 + tile * 64 + g * 8);
                *(uint4*)&WT[(g * 64 + (row ^ g)) * 8] = v;
            }
            __syncthreads();
#pragma unroll
            for (int st = 0; st < 4; ++st) {
                s16x8 b0 = *(const s16x8*)&WH[((st * 8 + qd) * 16 + (lm ^ qd)) * 8];
                s16x8 b1 = *(const s16x8*)&WH[((st * 8 + qd + 4) * 16 + (lm ^ (qd + 4))) * 8];
                f32x4 z = {0.f, 0.f, 0.f, 0.f};
                z = __builtin_amdgcn_mfma_f32_16x16x32_bf16(a0, b0, z, 0, 0, 0);
                z = __builtin_amdgcn_mfma_f32_16x16x32_bf16(a1, b1, z, 0, 0, 0);
                int g2 = st * 2 + (lm >> 3);       // [0,8)
#pragma unroll
                for (int r = 0; r < 4; ++r) {
                    float e = __expf(z[r] - mM[r]);
                    float a = e * invZ[r];
                    float tt = a - SHRINKc;
                    float sres = fmaxf(tt, 0.f) * a / (fabsf(tt) + 1e-12f);
                    L1[r] += sres;
                    int rr = qd * 4 + r;
                    ST[(g2 * 16 + (rr ^ g2)) * 8 + (lm & 7)] = f2b(sres);
                }
            }
#pragma unroll
            for (int ks = 0; ks < 2; ++ks) {
                int g = ks * 4 + qd;               // [0,8)
                s16x8 af = *(const s16x8*)&ST[(g * 16 + (lm ^ g)) * 8];
#pragma unroll
                for (int n = 0; n < 4; ++n) {
                    s16x8 bf = *(const s16x8*)&WT[(g * 64 + ((n * 16 + lm) ^ g)) * 8];
                    oacc[n] = __builtin_amdgcn_mfma_f32_16x16x32_bf16(af, bf, oacc[n], 0, 0, 0);
                }
            }
        }
#pragma unroll
        for (int r = 0; r < 4; ++r) {
#pragma unroll
            for (int off = 1; off < 16; off <<= 1) L1[r] += __shfl_xor(L1[r], off);
            L1[r] = 1.f / fmaxf(L1[r], 1e-12f);
        }
#pragma unroll
        for (int n = 0; n < 4; ++n)
#pragma unroll
            for (int r = 0; r < 4; ++r)
                PoutH[(size_t)(pb + 16 * w + qd * 4 + r) * 64 + n * 16 + lm] =
                    f2b(oacc[n][r] * L1[r]);
    } else if (bid < 296) {
        // ================= dist6 role: bin ring search =================
        int v = (bid - 256) * 256 + t;             // 40*256 = 10240
        if (v >= NVc) return;
        int xi = coords[v * 4 + 1], yi = coords[v * 4 + 2];
        float x = (float)xi, y = (float)yi;
        int bx = xi >> 4; if (bx > NBX - 1) bx = NBX - 1;
        int by = yi >> 4; if (by > NBY - 1) by = NBY - 1;
        unsigned kk[6] = {~0u, ~0u, ~0u, ~0u, ~0u, ~0u};
        for (int r = 0; r < 32; ++r) {
            int x0 = bx - r, x1 = bx + r, y0 = by - r, y1 = by + r;
            for (int cy = y0; cy <= y1; ++cy) {
                if (cy < 0 || cy > NBY - 1) continue;
                int step = (cy == y0 || cy == y1) ? 1 : (x1 > x0 ? x1 - x0 : 1);
                for (int cx = x0; cx <= x1; cx += step) {
                    if (cx < 0 || cx > NBX - 1) continue;
                    int b = cy * NBX + cx;
                    int s0 = binStart[b], s1 = binStart[b + 1];
                    for (int s = s0; s < s1; ++s) {
                        float4 p = binPC[s];
                        float e1 = x - p.x, e2 = y - p.y;
                        float d2 = fmaf(e1, e1, fmaf(e2, e2, p.z));
                        unsigned tk = (__float_as_uint(d2) & 0xFFFFC000u) | __float_as_uint(p.w);
                        kk[5] = med3u(kk[4], kk[5], tk);
                        kk[4] = med3u(kk[3], kk[4], tk);
                        kk[3] = med3u(kk[2], kk[3], tk);
                        kk[2] = med3u(kk[1], kk[2], tk);
                        kk[1] = med3u(kk[0], kk[1], tk);
                        kk[0] = kk[0] < tk ? kk[0] : tk;
                    }
                }
            }
            if (kk[2] != ~0u) {
                float d3 = __uint_as_float(kk[2] & 0xFFFFC000u);
                if (256.f * (float)(r * r) > d3 * 1.004f + 1e-3f) break;
            }
        }
#pragma unroll
        for (int j2 = 0; j2 < 6; ++j2) dIdx6[v * 6 + j2] = (int)(kk[j2] & 16383u);
    } else {
        // ================= score role: MFMA top-4, dbuf LDS, butterfly merge =================
        int sb = bid - 296;                        // 0..2511
        int pb = (sb >> 4) * 64;                   // 157 pillar tiles
        int cb = (sb & 15) * 1024;                 // 16 chunks
        const u16* arow = pillarH + (size_t)(pb + 16 * w + lm) * 64 + qd * 8;
        s16x8 a0 = *(const s16x8*)arow;
        s16x8 a1 = *(const s16x8*)(arow + 32);
        int so[4], doff[4];
#pragma unroll
        for (int r = 0; r < 4; ++r) {
            int q = t + 256 * r;
            int row = q >> 3, g = q & 7;
            so[r] = row * 64 + g * 8;
            doff[r] = (((row >> 4) * 8 + g) * 16 + ((row & 15) ^ g)) * 8;
        }
        uint4 pre[4];
        const u16* src = pfeatH + (size_t)cb * 64;
#pragma unroll
        for (int r = 0; r < 4; ++r) pre[r] = *(const uint4*)(src + so[r]);
#pragma unroll
        for (int r = 0; r < 4; ++r) *(uint4*)&smem.bf[0][doff[r]] = pre[r];
        unsigned sk[4][4];
#pragma unroll
        for (int r = 0; r < 4; ++r)
#pragma unroll
            for (int j = 0; j < 4; ++j) sk[r][j] = 0u;
        for (int s = 0; s < 8; ++s) {
            __syncthreads();                       // BF[s&1] ready; prior compute done
            if (s < 7) {
                const u16* s2 = src + (size_t)(s + 1) * 128 * 64;
#pragma unroll
                for (int r = 0; r < 4; ++r) pre[r] = *(const uint4*)(s2 + so[r]);
            }
            const u16* B = &smem.bf[s & 1][0];
#pragma unroll
            for (int pt = 0; pt < 8; ++pt) {
                s16x8 b0 = *(const s16x8*)&B[(((pt * 8 + qd) * 16) + (lm ^ qd)) * 8];
                s16x8 b1 = *(const s16x8*)&B[(((pt * 8 + qd + 4) * 16) + (lm ^ (qd + 4))) * 8];
                f32x4 acc = {256.f, 256.f, 256.f, 256.f};
                acc = __builtin_amdgcn_mfma_f32_16x16x32_bf16(a0, b0, acc, 0, 0, 0);
                acc = __builtin_amdgcn_mfma_f32_16x16x32_bf16(a1, b1, acc, 0, 0, 0);
                unsigned idf = (unsigned)(1023 - (s * 128 + pt * 16 + lm));
#pragma unroll
                for (int r = 0; r < 4; ++r) {
                    unsigned key = (__float_as_uint(acc[r]) & 0xFFFFFC00u) | idf;
                    sk[r][3] = med3u(sk[r][2], sk[r][3], key);
                    sk[r][2] = med3u(sk[r][1], sk[r][2], key);
                    sk[r][1] = med3u(sk[r][0], sk[r][1], key);
                    sk[r][0] = sk[r][0] > key ? sk[r][0] : key;
                }
            }
            if (s < 7) {
#pragma unroll
                for (int r = 0; r < 4; ++r) *(uint4*)&smem.bf[(s + 1) & 1][doff[r]] = pre[r];
            }
        }
        // butterfly merge across the 16 lanes of each quad (verified R10)
#pragma unroll
        for (int off = 1; off < 16; off <<= 1) {
#pragma unroll
            for (int r = 0; r < 4; ++r) {
                unsigned o0 = __shfl_xor(sk[r][0], off);
                unsigned o1 = __shfl_xor(sk[r][1], off);
                unsigned o2 = __shfl_xor(sk[r][2], off);
                unsigned o3 = __shfl_xor(sk[r][3], off);
                sk[r][3] = med3u(sk[r][2], sk[r][3], o0);
                sk[r][2] = med3u(sk[r][1], sk[r][2], o0);
                sk[r][1] = med3u(sk[r][0], sk[r][1], o0);
                sk[r][0] = sk[r][0] > o0 ? sk[r][0] : o0;
                sk[r][3] = med3u(sk[r][2], sk[r][3], o1);
                sk[r][2] = med3u(sk[r][1], sk[r][2], o1);
                sk[r][1] = med3u(sk[r][0], sk[r][1], o1);
                sk[r][0] = sk[r][0] > o1 ? sk[r][0] : o1;
                sk[r][3] = med3u(sk[r][2], sk[r][3], o2);
                sk[r][2] = med3u(sk[r][1], sk[r][2], o2);
                sk[r][1] = med3u(sk[r][0], sk[r][1], o2);
                sk[r][0] = sk[r][0] > o2 ? sk[r][0] : o2;
                sk[r][3] = med3u(sk[r][2], sk[r][3], o3);
                sk[r][2] = med3u(sk[r][1], sk[r][2], o3);
                sk[r][1] = med3u(sk[r][0], sk[r][1], o3);
                sk[r][0] = sk[r][0] > o3 ? sk[r][0] : o3;
            }
        }
        if (lm == 0) {
            int chunk = sb & 15;
#pragma unroll
            for (int r = 0; r < 4; ++r) {
                int gpr = pb + 16 * w + qd * 4 + r;
                if (gpr < NVc) {
                    int4 v;
                    v.x = cb + 1023 - (int)(sk[r][0] & 1023u);
                    v.y = cb + 1023 - (int)(sk[r][1] & 1023u);
                    v.z = cb + 1023 - (int)(sk[r][2] & 1023u);
                    v.w = cb + 1023 - (int)(sk[r][3] & 1023u);
                    *(int4*)&sIdx[(chunk * NVc + gpr) * 4] = v;
                }
            }
        }
    }
}

// ---------------- FUSED-2: proj2 (bid<256, AD-staged) | fp64 rerank ----------------
__global__ __launch_bounds__(256) void k_fused2(const u16* __restrict__ PoutH,
                                                const u16* __restrict__ badaptH,
                                                const float* __restrict__ pillar,
                                                const int* __restrict__ coords,
                                                const float* __restrict__ pfeat,
                                                const float* __restrict__ pcoord,
                                                const int* __restrict__ sIdx,
                                                const int* __restrict__ dIdx6,
                                                float* __restrict__ Q,
                                                int* __restrict__ idx_f,
                                                int* __restrict__ idx_c) {
    __shared__ u16 AD[12288];
    int bid = blockIdx.x;
    int t = threadIdx.x;
    if (bid < 256) {
        int w = t >> 6, l = t & 63;
        int lm = l & 15, qd = l >> 4;
        int pb = bid * 64;
#pragma unroll
        for (int r = 0; r < 6; ++r) {
            int q = t + 256 * r;
            int row = q >> 3, g = q & 7;
            uint4 v = *(const uint4*)(badaptH + (size_t)row * 64 + g * 8);
            *(uint4*)&AD[(((row >> 4) * 8 + g) * 16 + ((row & 15) ^ g)) * 8] = v;
        }
        const u16* arow = PoutH + (size_t)(pb + 16 * w + lm) * 64 + qd * 8;
        s16x8 a0 = *(const s16x8*)arow;
        s16x8 a1 = *(const s16x8*)(arow + 32);
        __syncthreads();
        f32x4 acc[12];
#pragma unroll
        for (int nt = 0; nt < 12; ++nt) {
            s16x8 b0 = *(const s16x8*)&AD[(((nt * 8 + qd) * 16) + (lm ^ qd)) * 8];
            s16x8 b1 = *(const s16x8*)&AD[(((nt * 8 + qd + 4) * 16) + (lm ^ (qd + 4))) * 8];
            f32x4 z = {0.f, 0.f, 0.f, 0.f};
            z = __builtin_amdgcn_mfma_f32_16x16x32_bf16(a0, b0, z, 0, 0, 0);
            z = __builtin_amdgcn_mfma_f32_16x16x32_bf16(a1, b1, z, 0, 0, 0);
            acc[nt] = z;
        }
#pragma unroll
        for (int nt = 0; nt < 12; ++nt)
#pragma unroll
            for (int r = 0; r < 4; ++r)
                Q[(size_t)(pb + 16 * w + qd * 4 + r) * 192 + nt * 16 + lm] = acc[nt][r];
    } else {
        int wv = t >> 6, l = t & 63;
        int v = (bid - 256) * 4 + wv;
        int chunk = l >> 2, slot = l & 3;
        int ps = sIdx[(chunk * NVc + v) * 4 + slot];
        int pd = dIdx6[v * 6 + (l < 6 ? l : 0)];
        double s = 0.0;
#pragma unroll
        for (int i = 0; i < 16; ++i) {
            float4 a = *(const float4*)(pillar + v * 64 + 4 * i);
            float4 b = *(const float4*)(pfeat + ps * 64 + 4 * i);
            s += (double)a.x * (double)b.x + (double)a.y * (double)b.y
               + (double)a.z * (double)b.z + (double)a.w * (double)b.w;
        }
        float4 qc = *(const float4*)(pcoord + pd * 4);
        double db_ = (double)coords[v * 4 + 0] - (double)qc.x;
        double dx_ = (double)coords[v * 4 + 1] - (double)qc.y;
        double dy_ = (double)coords[v * 4 + 2] - (double)qc.z;
        double dz_ = (double)coords[v * 4 + 3] - (double)qc.w;
        double d2 = db_ * db_ + dx_ * dx_ + dy_ * dy_ + dz_ * dz_;
        double sv = s; int sx = ps;
        for (int k = 0; k < 3; ++k) {
            double bv = sv; int bi = sx;
#pragma unroll
            for (int off = 32; off >= 1; off >>= 1) {
                double ov = __shfl_xor(bv, off);
                int    oi = __shfl_xor(bi, off);
                if (ov > bv || (ov == bv && oi < bi)) { bv = ov; bi = oi; }
            }
            if (l == 0) idx_f[v * 3 + k] = bi;
            if (sx == bi) { sv = -INFINITY; sx = 0x7fffffff; }
        }
        double dv = d2; int dx2 = pd;
        for (int k = 0; k < 3; ++k) {
            double bv = dv; int bi = dx2;
#pragma unroll
            for (int off = 32; off >= 1; off >>= 1) {
                double ov = __shfl_xor(bv, off);
                int    oi = __shfl_xor(bi, off);
                if (ov < bv || (ov == bv && oi < bi)) { bv = ov; bi = oi; }
            }
            if (l == 0) idx_c[v * 3 + k] = bi;
            if (dx2 == bi) { dv = INFINITY; dx2 = 0x7fffffff; }
        }
    }
}

// ---------------- gather-add + w logits + BN partial sums + cellMap scatter ----------------
__global__ __launch_bounds__(256) void k_gather(const float* __restrict__ Q,
                                                const int* __restrict__ idx_f,
                                                const int* __restrict__ idx_c,
                                                const float* __restrict__ pillar,
                                                const int* __restrict__ coords,
                                                const float* __restrict__ ww,
                                                float* __restrict__ f_pre,
                                                float* __restrict__ c_pre,
                                                float* __restrict__ w_pre,
                                                float* __restrict__ stats,
                                                int* __restrict__ cellMap) {
    __shared__ float red[4][4][64];
    __shared__ float redw[4][4];
    int t = threadIdx.x;
    int wv = t >> 6, l = t & 63;
    int base = blockIdx.x * 40;
    int vend = base + 40;
    if (t < 40) {
        int v = base + t;
        int cell = coords[v * 4 + 1] + coords[v * 4 + 2] * NXc + coords[v * 4 + 3];
        cellMap[cell] = v;
    }
    float fs = 0, fq = 0, cs = 0, cq = 0, ws0 = 0, wq0 = 0, ws1 = 0, wq1 = 0;
    float w0l = ww[l], w1l = ww[64 + l];
    for (int v = base + wv; v < vend; v += 4) {
        int if0 = idx_f[v * 3], if1 = idx_f[v * 3 + 1], if2 = idx_f[v * 3 + 2];
        float f = Q[if0 * 192 + l] + Q[if1 * 192 + 64 + l] + Q[if2 * 192 + 128 + l];
        f_pre[v * 64 + l] = f; fs += f; fq += f * f;
        int ic0 = idx_c[v * 3], ic1 = idx_c[v * 3 + 1], ic2 = idx_c[v * 3 + 2];
        float c = Q[ic0 * 192 + l] + Q[ic1 * 192 + 64 + l] + Q[ic2 * 192 + 128 + l];
        c_pre[v * 64 + l] = c; cs += c; cq += c * c;
        float pv = pillar[v * 64 + l];
        float a0 = pv * w0l, a1 = pv * w1l;
#pragma unroll
        for (int off = 32; off >= 1; off >>= 1) {
            a0 += __shfl_xor(a0, off);
            a1 += __shfl_xor(a1, off);
        }
        if (l == 0) { w_pre[v * 2] = a0; w_pre[v * 2 + 1] = a1; }
        ws0 += a0; wq0 += a0 * a0; ws1 += a1; wq1 += a1 * a1;
    }
    red[0][wv][l] = fs; red[1][wv][l] = fq; red[2][wv][l] = cs; red[3][wv][l] = cq;
    if (l == 0) { redw[wv][0] = ws0; redw[wv][1] = wq0; redw[wv][2] = ws1; redw[wv][3] = wq1; }
    __syncthreads();
    if (wv == 0) {
#pragma unroll
        for (int q = 0; q < 4; ++q) {
            float sum = red[q][0][l] + red[q][1][l] + red[q][2][l] + red[q][3][l];
            atomicAdd(&stats[q * 64 + l], sum);
        }
        if (l < 4) {
            float sum = redw[0][l] + redw[1][l] + redw[2][l] + redw[3][l];
            atomicAdd(&stats[256 + l], sum);
        }
    }
}

// ---------------- full-canvas write with inline BN/softmax aug ----------------
__global__ __launch_bounds__(256) void k_out2(const int* __restrict__ cellMap,
                                              const float* __restrict__ pillar,
                                              const float* __restrict__ f_pre,
                                              const float* __restrict__ c_pre,
                                              const float* __restrict__ w_pre,
                                              const float* __restrict__ stats,
                                              const float* __restrict__ g1,
                                              const float* __restrict__ b1,
                                              const float* __restrict__ g2,
                                              const float* __restrict__ b2,
                                              float* __restrict__ out) {
    int c4 = (blockIdx.x * 256 + threadIdx.x) * 4;
    if (c4 >= CELLS) return;
    int4 cm = *(const int4*)(cellMap + c4);
    const float invn = 1.0f / (float)NVc;
    float mw0 = stats[256] * invn, vw0 = stats[257] * invn - mw0 * mw0;
    float mw1 = stats[258] * invn, vw1 = stats[259] * invn - mw1 * mw1;
    float rw0 = rsqrtf(vw0 + 1e-3f), rw1 = rsqrtf(vw1 + 1e-3f);
    float g20 = g2[0], b20 = b2[0], g21 = g2[1], b21 = b2[1];
    float w0c[4], w1c[4];
    int cms[4] = {cm.x, cm.y, cm.z, cm.w};
#pragma unroll
    for (int k = 0; k < 4; ++k) {
        int c = cms[k];
        if (c >= 0) {
            float z0 = (w_pre[c * 2] - mw0) * rw0 * g20 + b20;
            float z1 = (w_pre[c * 2 + 1] - mw1) * rw1 * g21 + b21;
            float mz = fmaxf(z0, z1);
            float e0 = __expf(z0 - mz), e1 = __expf(z1 - mz);
            float wd = 1.f / (e0 + e1);
            w0c[k] = e0 * wd; w1c[k] = e1 * wd;
        } else { w0c[k] = 0.f; w1c[k] = 0.f; }
    }
    int f0 = blockIdx.y * 33;
    int f1 = f0 + 33; if (f1 > 131) f1 = 131;
    for (int f = f0; f < f1; ++f) {
        float4 val;
        if (f < 64) {
            val.x = cm.x >= 0 ? pillar[cm.x * 64 + f] : 0.f;
            val.y = cm.y >= 0 ? pillar[cm.y * 64 + f] : 0.f;
            val.z = cm.z >= 0 ? pillar[cm.z * 64 + f] : 0.f;
            val.w = cm.w >= 0 ? pillar[cm.w * 64 + f] : 0.f;
        } else if (f < 128) {
            int fa = f - 64;
            float mf = stats[fa] * invn;
            float rf = rsqrtf(stats[64 + fa] * invn - mf * mf + 1e-3f);
            float mc = stats[128 + fa] * invn;
            float rc = rsqrtf(stats[192 + fa] * invn - mc * mc + 1e-3f);
            float gg = g1[fa], bb = b1[fa];
            float* vv = (float*)&val;
#pragma unroll
            for (int k = 0; k < 4; ++k) {
                int c = cms[k];
                if (c >= 0) {
                    float fv = fmaxf((f_pre[c * 64 + fa] - mf) * rf * gg + bb, 0.f);
                    float cv = fmaxf((c_pre[c * 64 + fa] - mc) * rc * gg + bb, 0.f);
                    vv[k] = w0c[k] * fv + w1c[k] * cv;
                } else vv[k] = 0.f;
            }
        } else if (f == 128) {
            val.x = cm.x >= 0 ? (float)((c4 + 0) / NXc) : 0.f;
            val.y = cm.y >= 0 ? (float)((c4 + 1) / NXc) : 0.f;
            val.z = cm.z >= 0 ? (float)((c4 + 2) / NXc) : 0.f;
            val.w = cm.w >= 0 ? (float)((c4 + 3) / NXc) : 0.f;
        } else if (f == 129) {
            val = make_float4(0.f, 0.f, 0.f, 0.f);
        } else {
            val.x = cm.x >= 0 ? (float)((c4 + 0) % NXc) : 0.f;
            val.y = cm.y >= 0 ? (float)((c4 + 1) % NXc) : 0.f;
            val.z = cm.z >= 0 ? (float)((c4 + 2) % NXc) : 0.f;
            val.w = cm.w >= 0 ? (float)((c4 + 3) % NXc) : 0.f;
        }
        *(float4*)(out + (size_t)f * CELLS + c4) = val;
    }
}

extern "C" void kernel_launch(void* const* d_in, const int* in_sizes, int n_in,
                              void* d_out, int out_size, void* d_ws, size_t ws_size,
                              hipStream_t stream) {
    const float* pillar = (const float*)d_in[0];
    const int*   coords = (const int*)d_in[1];
    const float* pfeat  = (const float*)d_in[2];
    const float* pcoord = (const float*)d_in[3];
    const float* adapt  = (const float*)d_in[4];
    const float* bn1g   = (const float*)d_in[5];
    const float* bn1b   = (const float*)d_in[6];
    const float* ww     = (const float*)d_in[7];
    const float* bn2g   = (const float*)d_in[8];
    const float* bn2b   = (const float*)d_in[9];
    const float* memw   = (const float*)d_in[10];
    float* out = (float*)d_out;
    float* ws  = (float*)d_ws;
    // workspace layout (float offsets)
    u16*   PoutH = (u16*)(ws + 0);                 // 1,048,576 u16
    float* Q     = ws + 1048576;                   // 3,145,728 fl
    int*   sIdx  = (int*)(ws + 4194304);           // 640,000
    int*   binStart  = (int*)(ws + 4834304);       // 838
    int*   dIdx6     = (int*)(ws + 4836824);       // 60,000
    float4* binPC    = (float4*)(ws + 4896824);    // 65,536 fl
    u16*   memwH   = (u16*)(ws + 4970000);         // 65,536 u16
    u16*   memwTH  = (u16*)(ws + 5002768);         // 65,536 u16
    u16*   badaptH = (u16*)(ws + 5035536);         // 12,288 u16
    int*   idxf  = (int*)(ws + 5474304);           // 30,000
    int*   idxc  = (int*)(ws + 5504304);           // 30,000
    float* fpre  = ws + 5534304;                   // 640,000
    float* cpre  = ws + 6174304;                   // 640,000
    float* wpre  = ws + 6814304;                   // 20,000
    float* stats = ws + 6834304;                   // 260
    int*   cellMap = (int*)(ws + 6840000);         // 214,272 ints
    // bf16 feature buffers overlap fpre/cpre (dead until k_gather writes them)
    u16* pillarH = (u16*)(ws + 5534304);           // 643,072 u16
    u16* pfeatH  = pillarH + (size_t)NVPAD * 64;   // 1,048,576 u16

    k_init  <<<7168, 256, 0, stream>>>(pillar, pfeat, memw, adapt, stats, cellMap,
                                       pillarH, pfeatH, memwH, memwTH, badaptH);
    k_pre   <<<1, 1024, 0, stream>>>(pcoord, binStart, binPC);
    k_fused <<<2808, 256, 0, stream>>>(pillarH, pfeatH, memwH, memwTH, coords,
                                       binPC, binStart, PoutH, dIdx6, sIdx);
    k_fused2<<<2756, 256, 0, stream>>>(PoutH, badaptH, pillar, coords, pfeat, pcoord,
                                       sIdx, dIdx6, Q, idxf, idxc);
    k_gather<<<250, 256, 0, stream>>>(Q, idxf, idxc, pillar, coords, ww,
                                      fpre, cpre, wpre, stats, cellMap);
    k_out2  <<<dim3(210, 4), 256, 0, stream>>>(cellMap, pillar, fpre, cpre, wpre, stats,
                                               bn1g, bn1b, bn2g, bn2b, out);
}

// Round 12
// 320.129 us; speedup vs baseline: 1.4399x; 1.0110x over previous
//
#include <hip/hip_runtime.h>
#include <math.h>

#define NXc 432
#define NYc 496
#define NVc 10000
#define NPc 16384
#define CELLS (NXc*NYc)          // 214272
#define SHRINKc 0.0025f
#define NVPAD 10048              // 157*64
#define NBX 27
#define NBY 31
#define NBIN (NBX*NBY)           // 837

typedef unsigned short u16;
typedef __attribute__((ext_vector_type(8))) short s16x8;   // 8 bf16
typedef __attribute__((ext_vector_type(4))) float f32x4;

// C median-of-3: LLVM AMDGPU backend pattern-matches this to v_med3_u32
// (no asm operand-pinning moves).
__device__ __forceinline__ unsigned med3u(unsigned a, unsigned b, unsigned c) {
    unsigned mn = a < b ? a : b;
    unsigned mx = a > b ? a : b;
    unsigned m2 = mx < c ? mx : c;
    return mn > m2 ? mn : m2;
}

// ---------------- fp32 -> bf16 (RNE) ----------------
__device__ __forceinline__ u16 f2b(float x) {
    unsigned u = __float_as_uint(x);
    unsigned r = (u + 0x7fffu + ((u >> 16) & 1u)) >> 16;
    return (u16)r;
}

// ---------------- init (bid<1792): zero+casts | pre (bid==1792): hist+scan+fill ----------------
__global__ __launch_bounds__(1024) void k_init(const float* __restrict__ pillar,
                                               const float* __restrict__ pfeat,
                                               const float* __restrict__ memw,
                                               const float* __restrict__ adapt,
                                               const float* __restrict__ pcoord,
                                               float* __restrict__ stats,
                                               int* __restrict__ cellMap,
                                               u16* __restrict__ pillarH,
                                               u16* __restrict__ pfeatH,
                                               u16* __restrict__ memwH,
                                               u16* __restrict__ memwTH,
                                               u16* __restrict__ badaptH,
                                               int* __restrict__ binStart,
                                               float4* __restrict__ binPC) {
    __shared__ int hcnt[1024];
    __shared__ int sc[1024];
    __shared__ int cur[1024];
    int bid = blockIdx.x;
    int t = threadIdx.x;
    if (bid < 1792) {
        int gid = bid * 1024 + t;                  // 1792*1024 = 1835008 exactly
        if (gid < CELLS) cellMap[gid] = -1;
        if (gid < 260) stats[gid] = 0.f;
        const int N1 = NVPAD * 64;                 // 643072
        const int N2 = N1 + NPc * 64;              // 1691648
        const int N3 = N2 + 65536;                 // 1757184
        const int N4 = N3 + 65536;                 // 1822720 (+12288 = 1835008)
        if (gid < N1) {
            int v = gid >> 6;
            pillarH[gid] = f2b(v < NVc ? pillar[gid] : 0.f);
        } else if (gid < N2) {
            pfeatH[gid - N1] = f2b(pfeat[gid - N1]);
        } else if (gid < N3) {
            memwH[gid - N2] = f2b(memw[gid - N2]);
        } else if (gid < N4) {
            int i = gid - N3;
            int d = i >> 10, j = i & 1023;
            memwTH[i] = f2b(memw[j * 64 + d]);     // memwT[d][j]
        } else {
            int i = gid - N4;                      // 0..12287: Badapt[c][d]
            int c = i >> 6, d = i & 63;
            badaptH[i] = f2b(adapt[(c & 63) * 192 + (c >> 6) * 64 + d]);
        }
    } else {
        // -------- pre role: histogram + exclusive scan + bin fill --------
        hcnt[t] = 0;
        __syncthreads();
        for (int j = t; j < NPc; j += 1024) {
            float4 pc = *(const float4*)(pcoord + j * 4);
            int bx = (int)(pc.y * 0.0625f); if (bx > NBX - 1) bx = NBX - 1;
            int by = (int)(pc.z * 0.0625f); if (by > NBY - 1) by = NBY - 1;
            atomicAdd(&hcnt[by * NBX + bx], 1);
        }
        __syncthreads();
        int vcount = (t < NBIN) ? hcnt[t] : 0;
        sc[t] = vcount;
        __syncthreads();
        for (int off = 1; off < 1024; off <<= 1) {
            int add = (t >= off) ? sc[t - off] : 0;
            __syncthreads();
            sc[t] += add;
            __syncthreads();
        }
        int excl = sc[t] - vcount;
        cur[t] = excl;
        if (t <= NBIN) binStart[t] = excl;
        __syncthreads();
        for (int j = t; j < NPc; j += 1024) {
            float4 pc = *(const float4*)(pcoord + j * 4);
            int bx = (int)(pc.y * 0.0625f); if (bx > NBX - 1) bx = NBX - 1;
            int by = (int)(pc.z * 0.0625f); if (by > NBY - 1) by = NBY - 1;
            int slot = atomicAdd(&cur[by * NBX + bx], 1);
            binPC[slot] = make_float4(pc.y, pc.z, pc.w * pc.w, __uint_as_float((unsigned)j));
        }
    }
}

// ---------------- FUSED: mem (bid<256) | dist6 (256..295) | score (296..2807) ----------------
__global__ __launch_bounds__(256) void k_fused(const u16* __restrict__ pillarH,
                                               const u16* __restrict__ pfeatH,
                                               const u16* __restrict__ memwH,
                                               const u16* __restrict__ memwTH,
                                               const int* __restrict__ coords,
                                               const float4* __restrict__ binPC,
                                               const int* __restrict__ binStart,
                                               u16* __restrict__ PoutH,
                                               int* __restrict__ dIdx6,
                                               int* __restrict__ sIdx) {
    __shared__ union {
        u16 bf[2][8192];                           // score role: 32 KB dbuf
        struct { u16 wh[4096]; u16 wt[4096]; u16 st[4][1024]; } m;   // mem role: 24 KB
    } smem;
    int bid = blockIdx.x;
    int t = threadIdx.x;
    int w = t >> 6, l = t & 63;
    int lm = l & 15, qd = l >> 4;

    if (bid < 256) {
        // ================= mem role: streaming memory_lookup, 64-row LDS tiles =================
        int pb = bid * 64;
        u16* WH = smem.m.wh;
        u16* WT = smem.m.wt;
        u16* ST = &smem.m.st[w][0];
        const u16* arow = pfeatH + (size_t)(pb + 16 * w + lm) * 64 + qd * 8;
        s16x8 a0 = *(const s16x8*)arow;
        s16x8 a1 = *(const s16x8*)(arow + 32);
        float mM[4] = {-INFINITY, -INFINITY, -INFINITY, -INFINITY};
        float Zs[4] = {0.f, 0.f, 0.f, 0.f};
        for (int tile = 0; tile < 16; ++tile) {
            __syncthreads();
#pragma unroll
            for (int r = 0; r < 2; ++r) {
                int q = t + 256 * r;               // 512 granules
                int row = q >> 3, g = q & 7;
                uint4 v = *(const uint4*)(memwH + (size_t)(tile * 64 + row) * 64 + g * 8);
                *(uint4*)&WH[(((row >> 4) * 8 + g) * 16 + ((row & 15) ^ g)) * 8] = v;
            }
            __syncthreads();
            f32x4 acc[4];
#pragma unroll
            for (int st = 0; st < 4; ++st) {
                s16x8 b0 = *(const s16x8*)&WH[((st * 8 + qd) * 16 + (lm ^ qd)) * 8];
                s16x8 b1 = *(const s16x8*)&WH[((st * 8 + qd + 4) * 16 + (lm ^ (qd + 4))) * 8];
                f32x4 z = {0.f, 0.f, 0.f, 0.f};
                z = __builtin_amdgcn_mfma_f32_16x16x32_bf16(a0, b0, z, 0, 0, 0);
                z = __builtin_amdgcn_mfma_f32_16x16x32_bf16(a1, b1, z, 0, 0, 0);
                acc[st] = z;
            }
#pragma unroll
            for (int r = 0; r < 4; ++r) {
                float tmax = acc[0][r];
#pragma unroll
                for (int st = 1; st < 4; ++st) tmax = fmaxf(tmax, acc[st][r]);
                float mn = fmaxf(mM[r], tmax);
                float zacc = Zs[r] * __expf(mM[r] - mn);
#pragma unroll
                for (int st = 0; st < 4; ++st) zacc += __expf(acc[st][r] - mn);
                mM[r] = mn; Zs[r] = zacc;
            }
        }
#pragma unroll
        for (int r = 0; r < 4; ++r) {
#pragma unroll
            for (int off = 1; off < 16; off <<= 1) {
                float om = __shfl_xor(mM[r], off);
                float oz = __shfl_xor(Zs[r], off);
                float mn = fmaxf(mM[r], om);
                Zs[r] = Zs[r] * __expf(mM[r] - mn) + oz * __expf(om - mn);
                mM[r] = mn;
            }
        }
        float invZ[4], L1[4] = {0.f, 0.f, 0.f, 0.f};
#pragma unroll
        for (int r = 0; r < 4; ++r) invZ[r] = 1.f / Zs[r];
        f32x4 oacc[4];
#pragma unroll
        for (int n = 0; n < 4; ++n) oacc[n] = (f32x4){0.f, 0.f, 0.f, 0.f};
        for (int tile = 0; tile < 16; ++tile) {
            __syncthreads();
#pragma unroll
            for (int r = 0; r < 2; ++r) {
                int q = t + 256 * r;
                int row = q >> 3, g = q & 7;
                uint4 v = *(const uint4*)(memwH + (size_t)(tile * 64 + row) * 64 + g * 8);
                *(uint4*)&WH[(((row >> 4) * 8 + g) * 16 + ((row & 15) ^ g)) * 8] = v;
            }
#pragma unroll
            for (int r = 0; r < 2; ++r) {
                int q = t + 256 * r;
                int row = q >> 3, g = q & 7;   // row = n in [0,64)
                uint4 v = *(const uint4*)(memwTH + (size_t)row * 1024 + tile * 64 + g * 8);
                *(uint4*)&WT[(g * 64 + (row ^ g)) * 8] = v;
            }
            __syncthreads();
#pragma unroll
            for (int st = 0; st < 4; ++st) {
                s16x8 b0 = *(const s16x8*)&WH[((st * 8 + qd) * 16 + (lm ^ qd)) * 8];
                s16x8 b1 = *(const s16x8*)&WH[((st * 8 + qd + 4) * 16 + (lm ^ (qd + 4))) * 8];
                f32x4 z = {0.f, 0.f, 0.f, 0.f};
                z = __builtin_amdgcn_mfma_f32_16x16x32_bf16(a0, b0, z, 0, 0, 0);
                z = __builtin_amdgcn_mfma_f32_16x16x32_bf16(a1, b1, z, 0, 0, 0);
                int g2 = st * 2 + (lm >> 3);       // [0,8)
#pragma unroll
                for (int r = 0; r < 4; ++r) {
                    float e = __expf(z[r] - mM[r]);
                    float a = e * invZ[r];
                    float tt = a - SHRINKc;
                    float sres = fmaxf(tt, 0.f) * a / (fabsf(tt) + 1e-12f);
                    L1[r] += sres;
                    int rr = qd * 4 + r;
                    ST[(g2 * 16 + (rr ^ g2)) * 8 + (lm & 7)] = f2b(sres);
                }
            }
#pragma unroll
            for (int ks = 0; ks < 2; ++ks) {
                int g = ks * 4 + qd;               // [0,8)
                s16x8 af = *(const s16x8*)&ST[(g * 16 + (lm ^ g)) * 8];
#pragma unroll
                for (int n = 0; n < 4; ++n) {
                    s16x8 bf = *(const s16x8*)&WT[(g * 64 + ((n * 16 + lm) ^ g)) * 8];
                    oacc[n] = __builtin_amdgcn_mfma_f32_16x16x32_bf16(af, bf, oacc[n], 0, 0, 0);
                }
            }
        }
#pragma unroll
        for (int r = 0; r < 4; ++r) {
#pragma unroll
            for (int off = 1; off < 16; off <<= 1) L1[r] += __shfl_xor(L1[r], off);
            L1[r] = 1.f / fmaxf(L1[r], 1e-12f);
        }
#pragma unroll
        for (int n = 0; n < 4; ++n)
#pragma unroll
            for (int r = 0; r < 4; ++r)
                PoutH[(size_t)(pb + 16 * w + qd * 4 + r) * 64 + n * 16 + lm] =
                    f2b(oacc[n][r] * L1[r]);
    } else if (bid < 296) {
        // ================= dist6 role: bin ring search =================
        int v = (bid - 256) * 256 + t;             // 40*256 = 10240
        if (v >= NVc) return;
        int xi = coords[v * 4 + 1], yi = coords[v * 4 + 2];
        float x = (float)xi, y = (float)yi;
        int bx = xi >> 4; if (bx > NBX - 1) bx = NBX - 1;
        int by = yi >> 4; if (by > NBY - 1) by = NBY - 1;
        unsigned kk[6] = {~0u, ~0u, ~0u, ~0u, ~0u, ~0u};
        for (int r = 0; r < 32; ++r) {
            int x0 = bx - r, x1 = bx + r, y0 = by - r, y1 = by + r;
            for (int cy = y0; cy <= y1; ++cy) {
                if (cy < 0 || cy > NBY - 1) continue;
                int step = (cy == y0 || cy == y1) ? 1 : (x1 > x0 ? x1 - x0 : 1);
                for (int cx = x0; cx <= x1; cx += step) {
                    if (cx < 0 || cx > NBX - 1) continue;
                    int b = cy * NBX + cx;
                    int s0 = binStart[b], s1 = binStart[b + 1];
                    for (int s = s0; s < s1; ++s) {
                        float4 p = binPC[s];
                        float e1 = x - p.x, e2 = y - p.y;
                        float d2 = fmaf(e1, e1, fmaf(e2, e2, p.z));
                        unsigned tk = (__float_as_uint(d2) & 0xFFFFC000u) | __float_as_uint(p.w);
                        kk[5] = med3u(kk[4], kk[5], tk);
                        kk[4] = med3u(kk[3], kk[4], tk);
                        kk[3] = med3u(kk[2], kk[3], tk);
                        kk[2] = med3u(kk[1], kk[2], tk);
                        kk[1] = med3u(kk[0], kk[1], tk);
                        kk[0] = kk[0] < tk ? kk[0] : tk;
                    }
                }
            }
            if (kk[2] != ~0u) {
                float d3 = __uint_as_float(kk[2] & 0xFFFFC000u);
                if (256.f * (float)(r * r) > d3 * 1.004f + 1e-3f) break;
            }
        }
#pragma unroll
        for (int j2 = 0; j2 < 6; ++j2) dIdx6[v * 6 + j2] = (int)(kk[j2] & 16383u);
    } else {
        // ================= score role: MFMA top-4, dbuf LDS, butterfly merge =================
        int sb = bid - 296;                        // 0..2511
        int pb = (sb >> 4) * 64;                   // 157 pillar tiles
        int cb = (sb & 15) * 1024;                 // 16 chunks
        const u16* arow = pillarH + (size_t)(pb + 16 * w + lm) * 64 + qd * 8;
        s16x8 a0 = *(const s16x8*)arow;
        s16x8 a1 = *(const s16x8*)(arow + 32);
        int so[4], doff[4];
#pragma unroll
        for (int r = 0; r < 4; ++r) {
            int q = t + 256 * r;
            int row = q >> 3, g = q & 7;
            so[r] = row * 64 + g * 8;
            doff[r] = (((row >> 4) * 8 + g) * 16 + ((row & 15) ^ g)) * 8;
        }
        uint4 pre[4];
        const u16* src = pfeatH + (size_t)cb * 64;
#pragma unroll
        for (int r = 0; r < 4; ++r) pre[r] = *(const uint4*)(src + so[r]);
#pragma unroll
        for (int r = 0; r < 4; ++r) *(uint4*)&smem.bf[0][doff[r]] = pre[r];
        unsigned sk[4][4];
#pragma unroll
        for (int r = 0; r < 4; ++r)
#pragma unroll
            for (int j = 0; j < 4; ++j) sk[r][j] = 0u;
        for (int s = 0; s < 8; ++s) {
            __syncthreads();                       // BF[s&1] ready; prior compute done
            if (s < 7) {
                const u16* s2 = src + (size_t)(s + 1) * 128 * 64;
#pragma unroll
                for (int r = 0; r < 4; ++r) pre[r] = *(const uint4*)(s2 + so[r]);
            }
            const u16* B = &smem.bf[s & 1][0];
#pragma unroll
            for (int pt = 0; pt < 8; ++pt) {
                s16x8 b0 = *(const s16x8*)&B[(((pt * 8 + qd) * 16) + (lm ^ qd)) * 8];
                s16x8 b1 = *(const s16x8*)&B[(((pt * 8 + qd + 4) * 16) + (lm ^ (qd + 4))) * 8];
                f32x4 acc = {256.f, 256.f, 256.f, 256.f};
                acc = __builtin_amdgcn_mfma_f32_16x16x32_bf16(a0, b0, acc, 0, 0, 0);
                acc = __builtin_amdgcn_mfma_f32_16x16x32_bf16(a1, b1, acc, 0, 0, 0);
                unsigned idf = (unsigned)(1023 - (s * 128 + pt * 16 + lm));
#pragma unroll
                for (int r = 0; r < 4; ++r) {
                    unsigned key = (__float_as_uint(acc[r]) & 0xFFFFFC00u) | idf;
                    sk[r][3] = med3u(sk[r][2], sk[r][3], key);
                    sk[r][2] = med3u(sk[r][1], sk[r][2], key);
                    sk[r][1] = med3u(sk[r][0], sk[r][1], key);
                    sk[r][0] = sk[r][0] > key ? sk[r][0] : key;
                }
            }
            if (s < 7) {
#pragma unroll
                for (int r = 0; r < 4; ++r) *(uint4*)&smem.bf[(s + 1) & 1][doff[r]] = pre[r];
            }
        }
        // butterfly merge across the 16 lanes of each quad
#pragma unroll
        for (int off = 1; off < 16; off <<= 1) {
#pragma unroll
            for (int r = 0; r < 4; ++r) {
                unsigned o0 = __shfl_xor(sk[r][0], off);
                unsigned o1 = __shfl_xor(sk[r][1], off);
                unsigned o2 = __shfl_xor(sk[r][2], off);
                unsigned o3 = __shfl_xor(sk[r][3], off);
                sk[r][3] = med3u(sk[r][2], sk[r][3], o0);
                sk[r][2] = med3u(sk[r][1], sk[r][2], o0);
                sk[r][1] = med3u(sk[r][0], sk[r][1], o0);
                sk[r][0] = sk[r][0] > o0 ? sk[r][0] : o0;
                sk[r][3] = med3u(sk[r][2], sk[r][3], o1);
                sk[r][2] = med3u(sk[r][1], sk[r][2], o1);
                sk[r][1] = med3u(sk[r][0], sk[r][1], o1);
                sk[r][0] = sk[r][0] > o1 ? sk[r][0] : o1;
                sk[r][3] = med3u(sk[r][2], sk[r][3], o2);
                sk[r][2] = med3u(sk[r][1], sk[r][2], o2);
                sk[r][1] = med3u(sk[r][0], sk[r][1], o2);
                sk[r][0] = sk[r][0] > o2 ? sk[r][0] : o2;
                sk[r][3] = med3u(sk[r][2], sk[r][3], o3);
                sk[r][2] = med3u(sk[r][1], sk[r][2], o3);
                sk[r][1] = med3u(sk[r][0], sk[r][1], o3);
                sk[r][0] = sk[r][0] > o3 ? sk[r][0] : o3;
            }
        }
        if (lm == 0) {
            int chunk = sb & 15;
#pragma unroll
            for (int r = 0; r < 4; ++r) {
                int gpr = pb + 16 * w + qd * 4 + r;
                if (gpr < NVc) {
                    int4 v;
                    v.x = cb + 1023 - (int)(sk[r][0] & 1023u);
                    v.y = cb + 1023 - (int)(sk[r][1] & 1023u);
                    v.z = cb + 1023 - (int)(sk[r][2] & 1023u);
                    v.w = cb + 1023 - (int)(sk[r][3] & 1023u);
                    *(int4*)&sIdx[(chunk * NVc + gpr) * 4] = v;
                }
            }
        }
    }
}

// ---------------- FUSED-2: proj2 (bid<256, AD-staged) | fp64 rerank ----------------
__global__ __launch_bounds__(256) void k_fused2(const u16* __restrict__ PoutH,
                                                const u16* __restrict__ badaptH,
                                                const float* __restrict__ pillar,
                                                const int* __restrict__ coords,
                                                const float* __restrict__ pfeat,
                                                const float* __restrict__ pcoord,
                                                const int* __restrict__ sIdx,
                                                const int* __restrict__ dIdx6,
                                                float* __restrict__ Q,
                                                int* __restrict__ idx_f,
                                                int* __restrict__ idx_c) {
    __shared__ u16 AD[12288];
    int bid = blockIdx.x;
    int t = threadIdx.x;
    if (bid < 256) {
        int w = t >> 6, l = t & 63;
        int lm = l & 15, qd = l >> 4;
        int pb = bid * 64;
#pragma unroll
        for (int r = 0; r < 6; ++r) {
            int q = t + 256 * r;
            int row = q >> 3, g = q & 7;
            uint4 v = *(const uint4*)(badaptH + (size_t)row * 64 + g * 8);
            *(uint4*)&AD[(((row >> 4) * 8 + g) * 16 + ((row & 15) ^ g)) * 8] = v;
        }
        const u16* arow = PoutH + (size_t)(pb + 16 * w + lm) * 64 + qd * 8;
        s16x8 a0 = *(const s16x8*)arow;
        s16x8 a1 = *(const s16x8*)(arow + 32);
        __syncthreads();
        f32x4 acc[12];
#pragma unroll
        for (int nt = 0; nt < 12; ++nt) {
            s16x8 b0 = *(const s16x8*)&AD[(((nt * 8 + qd) * 16) + (lm ^ qd)) * 8];
            s16x8 b1 = *(const s16x8*)&AD[(((nt * 8 + qd + 4) * 16) + (lm ^ (qd + 4))) * 8];
            f32x4 z = {0.f, 0.f, 0.f, 0.f};
            z = __builtin_amdgcn_mfma_f32_16x16x32_bf16(a0, b0, z, 0, 0, 0);
            z = __builtin_amdgcn_mfma_f32_16x16x32_bf16(a1, b1, z, 0, 0, 0);
            acc[nt] = z;
        }
#pragma unroll
        for (int nt = 0; nt < 12; ++nt)
#pragma unroll
            for (int r = 0; r < 4; ++r)
                Q[(size_t)(pb + 16 * w + qd * 4 + r) * 192 + nt * 16 + lm] = acc[nt][r];
    } else {
        int wv = t >> 6, l = t & 63;
        int v = (bid - 256) * 4 + wv;
        int chunk = l >> 2, slot = l & 3;
        int ps = sIdx[(chunk * NVc + v) * 4 + slot];
        int pd = dIdx6[v * 6 + (l < 6 ? l : 0)];
        double s = 0.0;
#pragma unroll
        for (int i = 0; i < 16; ++i) {
            float4 a = *(const float4*)(pillar + v * 64 + 4 * i);
            float4 b = *(const float4*)(pfeat + ps * 64 + 4 * i);
            s += (double)a.x * (double)b.x + (double)a.y * (double)b.y
               + (double)a.z * (double)b.z + (double)a.w * (double)b.w;
        }
        float4 qc = *(const float4*)(pcoord + pd * 4);
        double db_ = (double)coords[v * 4 + 0] - (double)qc.x;
        double dx_ = (double)coords[v * 4 + 1] - (double)qc.y;
        double dy_ = (double)coords[v * 4 + 2] - (double)qc.z;
        double dz_ = (double)coords[v * 4 + 3] - (double)qc.w;
        double d2 = db_ * db_ + dx_ * dx_ + dy_ * dy_ + dz_ * dz_;
        double sv = s; int sx = ps;
        for (int k = 0; k < 3; ++k) {
            double bv = sv; int bi = sx;
#pragma unroll
            for (int off = 32; off >= 1; off >>= 1) {
                double ov = __shfl_xor(bv, off);
                int    oi = __shfl_xor(bi, off);
                if (ov > bv || (ov == bv && oi < bi)) { bv = ov; bi = oi; }
            }
            if (l == 0) idx_f[v * 3 + k] = bi;
            if (sx == bi) { sv = -INFINITY; sx = 0x7fffffff; }
        }
        double dv = d2; int dx2 = pd;
        for (int k = 0; k < 3; ++k) {
            double bv = dv; int bi = dx2;
#pragma unroll
            for (int off = 32; off >= 1; off >>= 1) {
                double ov = __shfl_xor(bv, off);
                int    oi = __shfl_xor(bi, off);
                if (ov < bv || (ov == bv && oi < bi)) { bv = ov; bi = oi; }
            }
            if (l == 0) idx_c[v * 3 + k] = bi;
            if (dx2 == bi) { dv = INFINITY; dx2 = 0x7fffffff; }
        }
    }
}

// ---------------- gather-add + w logits + BN partial sums + cellMap scatter ----------------
__global__ __launch_bounds__(256) void k_gather(const float* __restrict__ Q,
                                                const int* __restrict__ idx_f,
                                                const int* __restrict__ idx_c,
                                                const float* __restrict__ pillar,
                                                const int* __restrict__ coords,
                                                const float* __restrict__ ww,
                                                float* __restrict__ f_pre,
                                                float* __restrict__ c_pre,
                                                float* __restrict__ w_pre,
                                                float* __restrict__ stats,
                                                int* __restrict__ cellMap) {
    __shared__ float red[4][4][64];
    __shared__ float redw[4][4];
    int t = threadIdx.x;
    int wv = t >> 6, l = t & 63;
    int base = blockIdx.x * 40;
    int vend = base + 40;
    if (t < 40) {
        int v = base + t;
        int cell = coords[v * 4 + 1] + coords[v * 4 + 2] * NXc + coords[v * 4 + 3];
        cellMap[cell] = v;
    }
    float fs = 0, fq = 0, cs = 0, cq = 0, ws0 = 0, wq0 = 0, ws1 = 0, wq1 = 0;
    float w0l = ww[l], w1l = ww[64 + l];
    for (int v = base + wv; v < vend; v += 4) {
        int if0 = idx_f[v * 3], if1 = idx_f[v * 3 + 1], if2 = idx_f[v * 3 + 2];
        float f = Q[if0 * 192 + l] + Q[if1 * 192 + 64 + l] + Q[if2 * 192 + 128 + l];
        f_pre[v * 64 + l] = f; fs += f; fq += f * f;
        int ic0 = idx_c[v * 3], ic1 = idx_c[v * 3 + 1], ic2 = idx_c[v * 3 + 2];
        float c = Q[ic0 * 192 + l] + Q[ic1 * 192 + 64 + l] + Q[ic2 * 192 + 128 + l];
        c_pre[v * 64 + l] = c; cs += c; cq += c * c;
        float pv = pillar[v * 64 + l];
        float a0 = pv * w0l, a1 = pv * w1l;
#pragma unroll
        for (int off = 32; off >= 1; off >>= 1) {
            a0 += __shfl_xor(a0, off);
            a1 += __shfl_xor(a1, off);
        }
        if (l == 0) { w_pre[v * 2] = a0; w_pre[v * 2 + 1] = a1; }
        ws0 += a0; wq0 += a0 * a0; ws1 += a1; wq1 += a1 * a1;
    }
    red[0][wv][l] = fs; red[1][wv][l] = fq; red[2][wv][l] = cs; red[3][wv][l] = cq;
    if (l == 0) { redw[wv][0] = ws0; redw[wv][1] = wq0; redw[wv][2] = ws1; redw[wv][3] = wq1; }
    __syncthreads();
    if (wv == 0) {
#pragma unroll
        for (int q = 0; q < 4; ++q) {
            float sum = red[q][0][l] + red[q][1][l] + red[q][2][l] + red[q][3][l];
            atomicAdd(&stats[q * 64 + l], sum);
        }
        if (l < 4) {
            float sum = redw[0][l] + redw[1][l] + redw[2][l] + redw[3][l];
            atomicAdd(&stats[256 + l], sum);
        }
    }
}

// ---------------- full-canvas write with inline BN/softmax aug ----------------
__global__ __launch_bounds__(256) void k_out2(const int* __restrict__ cellMap,
                                              const float* __restrict__ pillar,
                                              const float* __restrict__ f_pre,
                                              const float* __restrict__ c_pre,
                                              const float* __restrict__ w_pre,
                                              const float* __restrict__ stats,
                                              const float* __restrict__ g1,
                                              const float* __restrict__ b1,
                                              const float* __restrict__ g2,
                                              const float* __restrict__ b2,
                                              float* __restrict__ out) {
    int c4 = (blockIdx.x * 256 + threadIdx.x) * 4;
    if (c4 >= CELLS) return;
    int4 cm = *(const int4*)(cellMap + c4);
    const float invn = 1.0f / (float)NVc;
    float mw0 = stats[256] * invn, vw0 = stats[257] * invn - mw0 * mw0;
    float mw1 = stats[258] * invn, vw1 = stats[259] * invn - mw1 * mw1;
    float rw0 = rsqrtf(vw0 + 1e-3f), rw1 = rsqrtf(vw1 + 1e-3f);
    float g20 = g2[0], b20 = b2[0], g21 = g2[1], b21 = b2[1];
    float w0c[4], w1c[4];
    int cms[4] = {cm.x, cm.y, cm.z, cm.w};
#pragma unroll
    for (int k = 0; k < 4; ++k) {
        int c = cms[k];
        if (c >= 0) {
            float z0 = (w_pre[c * 2] - mw0) * rw0 * g20 + b20;
            float z1 = (w_pre[c * 2 + 1] - mw1) * rw1 * g21 + b21;
            float mz = fmaxf(z0, z1);
            float e0 = __expf(z0 - mz), e1 = __expf(z1 - mz);
            float wd = 1.f / (e0 + e1);
            w0c[k] = e0 * wd; w1c[k] = e1 * wd;
        } else { w0c[k] = 0.f; w1c[k] = 0.f; }
    }
    int f0 = blockIdx.y * 33;
    int f1 = f0 + 33; if (f1 > 131) f1 = 131;
    for (int f = f0; f < f1; ++f) {
        float4 val;
        if (f < 64) {
            val.x = cm.x >= 0 ? pillar[cm.x * 64 + f] : 0.f;
            val.y = cm.y >= 0 ? pillar[cm.y * 64 + f] : 0.f;
            val.z = cm.z >= 0 ? pillar[cm.z * 64 + f] : 0.f;
            val.w = cm.w >= 0 ? pillar[cm.w * 64 + f] : 0.f;
        } else if (f < 128) {
            int fa = f - 64;
            float mf = stats[fa] * invn;
            float rf = rsqrtf(stats[64 + fa] * invn - mf * mf + 1e-3f);
            float mc = stats[128 + fa] * invn;
            float rc = rsqrtf(stats[192 + fa] * invn - mc * mc + 1e-3f);
            float gg = g1[fa], bb = b1[fa];
            float* vv = (float*)&val;
#pragma unroll
            for (int k = 0; k < 4; ++k) {
                int c = cms[k];
                if (c >= 0) {
                    float fv = fmaxf((f_pre[c * 64 + fa] - mf) * rf * gg + bb, 0.f);
                    float cv = fmaxf((c_pre[c * 64 + fa] - mc) * rc * gg + bb, 0.f);
                    vv[k] = w0c[k] * fv + w1c[k] * cv;
                } else vv[k] = 0.f;
            }
        } else if (f == 128) {
            val.x = cm.x >= 0 ? (float)((c4 + 0) / NXc) : 0.f;
            val.y = cm.y >= 0 ? (float)((c4 + 1) / NXc) : 0.f;
            val.z = cm.z >= 0 ? (float)((c4 + 2) / NXc) : 0.f;
            val.w = cm.w >= 0 ? (float)((c4 + 3) / NXc) : 0.f;
        } else if (f == 129) {
            val = make_float4(0.f, 0.f, 0.f, 0.f);
        } else {
            val.x = cm.x >= 0 ? (float)((c4 + 0) % NXc) : 0.f;
            val.y = cm.y >= 0 ? (float)((c4 + 1) % NXc) : 0.f;
            val.z = cm.z >= 0 ? (float)((c4 + 2) % NXc) : 0.f;
            val.w = cm.w >= 0 ? (float)((c4 + 3) % NXc) : 0.f;
        }
        *(float4*)(out + (size_t)f * CELLS + c4) = val;
    }
}

extern "C" void kernel_launch(void* const* d_in, const int* in_sizes, int n_in,
                              void* d_out, int out_size, void* d_ws, size_t ws_size,
                              hipStream_t stream) {
    const float* pillar = (const float*)d_in[0];
    const int*   coords = (const int*)d_in[1];
    const float* pfeat  = (const float*)d_in[2];
    const float* pcoord = (const float*)d_in[3];
    const float* adapt  = (const float*)d_in[4];
    const float* bn1g   = (const float*)d_in[5];
    const float* bn1b   = (const float*)d_in[6];
    const float* ww     = (const float*)d_in[7];
    const float* bn2g   = (const float*)d_in[8];
    const float* bn2b   = (const float*)d_in[9];
    const float* memw   = (const float*)d_in[10];
    float* out = (float*)d_out;
    float* ws  = (float*)d_ws;
    // workspace layout (float offsets)
    u16*   PoutH = (u16*)(ws + 0);                 // 1,048,576 u16
    float* Q     = ws + 1048576;                   // 3,145,728 fl
    int*   sIdx  = (int*)(ws + 4194304);           // 640,000
    int*   binStart  = (int*)(ws + 4834304);       // 838
    int*   dIdx6     = (int*)(ws + 4836824);       // 60,000
    float4* binPC    = (float4*)(ws + 4896824);    // 65,536 fl
    u16*   memwH   = (u16*)(ws + 4970000);         // 65,536 u16
    u16*   memwTH  = (u16*)(ws + 5002768);         // 65,536 u16
    u16*   badaptH = (u16*)(ws + 5035536);         // 12,288 u16
    int*   idxf  = (int*)(ws + 5474304);           // 30,000
    int*   idxc  = (int*)(ws + 5504304);           // 30,000
    float* fpre  = ws + 5534304;                   // 640,000
    float* cpre  = ws + 6174304;                   // 640,000
    float* wpre  = ws + 6814304;                   // 20,000
    float* stats = ws + 6834304;                   // 260
    int*   cellMap = (int*)(ws + 6840000);         // 214,272 ints
    // bf16 feature buffers overlap fpre/cpre (dead until k_gather writes them)
    u16* pillarH = (u16*)(ws + 5534304);           // 643,072 u16
    u16* pfeatH  = pillarH + (size_t)NVPAD * 64;   // 1,048,576 u16

    k_init  <<<1793, 1024, 0, stream>>>(pillar, pfeat, memw, adapt, pcoord, stats, cellMap,
                                        pillarH, pfeatH, memwH, memwTH, badaptH,
                                        binStart, binPC);
    k_fused <<<2808, 256, 0, stream>>>(pillarH, pfeatH, memwH, memwTH, coords,
                                       binPC, binStart, PoutH, dIdx6, sIdx);
    k_fused2<<<2756, 256, 0, stream>>>(PoutH, badaptH, pillar, coords, pfeat, pcoord,
                                       sIdx, dIdx6, Q, idxf, idxc);
    k_gather<<<250, 256, 0, stream>>>(Q, idxf, idxc, pillar, coords, ww,
                                      fpre, cpre, wpre, stats, cellMap);
    k_out2  <<<dim3(210, 4), 256, 0, stream>>>(cellMap, pillar, fpre, cpre, wpre, stats,
                                               bn1g, bn1b, bn2g, bn2b, out);
}